// Round 1
// baseline (1365.705 us; speedup 1.0000x reference)
//
#include <hip/hip_runtime.h>
#include <math.h>

// ---------------------------------------------------------------------------
// Problem constants
// ---------------------------------------------------------------------------
#define DM    256     // D_MODEL
#define NH    4       // heads
#define HD    64      // head dim
#define TS    40      // T_SEQ
#define TM1   39
#define BB    32      // batch
#define DFF   1024
#define DINO  384
#define NPATCH 256
#define VOCAB 4096

#define NTOK  24960   // 780*32 packed (t, p<=t, b) tokens
#define NQ2   1248    // 39*32

// Packed row id: r = (tri(t)+p)*32 + b, tri(t)=t(t+1)/2

// ---------------------------------------------------------------------------
// Workspace layout (float offsets). "big" region aliases ao0 / ff1-half / kv1
// (their lifetimes are strictly sequential).
// ---------------------------------------------------------------------------
#define OFF_EMB   0u                      /* 1280*256    =   327680 */
#define OFF_QKV0  327680u                 /* 1280*768    =   983040 */
#define OFF_X1    1310720u                /* 24960*256   =  6389760 */
#define OFF_H1    7700480u                /* 24960*256   =  6389760 */
#define OFF_BIG   14090240u               /* max(ao0 6389760, ff1half 12779520, kv1 12779520) */
#define OFF_AO1   26869760u               /* 1248*256    =   319488 */
#define OFF_X2    27189248u               /* 1248*256    =   319488 */
#define OFF_FF2   27508736u               /* 1248*1024   =  1277952 */
#define OFF_CTX   28786688u               /* 40*32*256   =   327680 */
#define OFF_PP    29114368u               /* 8192*256    =  2097152 */
#define OFF_CPB   31211520u               /* 1280*256    =   327680 */
#define OFF_U     31539200u               /* 1280*256    =   327680 */
#define OFF_S     31866880u               /* 1280        */
#define OFF_MAP   31868160u               /* ints: map1 24960 + map2 1248 */
#define WS_FLOATS (31868160u + 26208u)

// ---------------------------------------------------------------------------
// K0: init row maps + zero ctx[t=0]
// ---------------------------------------------------------------------------
__global__ void init_maps(int* __restrict__ map1, int* __restrict__ map2,
                          float* __restrict__ ctx)
{
    int idx = blockIdx.x * 256 + threadIdx.x;
    if (idx < BB * DM) ctx[idx] = 0.f;                     // ctx rows for t=0
    if (idx < NQ2) {
        int t = idx >> 5, b = idx & 31;
        map2[idx] = ((t * (t + 1)) / 2 + t) * 32 + b;      // h1 row of (t,b,p=t)
    }
    if (idx < NTOK) {
        int q = idx >> 5, b = idx & 31;                    // q = tri(t)+p
        int t = 0;
        while (((t + 1) * (t + 2)) / 2 <= q) ++t;
        int p = q - (t * (t + 1)) / 2;
        map1[idx] = b * TS + p;                            // emb row of token
    }
}

// ---------------------------------------------------------------------------
// K1: emb[b,p,:] = embedding[tokens[b,p]] + pos_emb[p]
// ---------------------------------------------------------------------------
__global__ __launch_bounds__(256) void embed_kernel(
    const int* __restrict__ tokens, const float* __restrict__ etab,
    const float* __restrict__ pos, float* __restrict__ emb)
{
    int r = blockIdx.x;            // b*40+p
    int p = r % TS;
    int j = threadIdx.x;
    int tok = tokens[r];
    emb[(size_t)r * DM + j] = etab[(size_t)tok * DM + j] + pos[p * DM + j];
}

// ---------------------------------------------------------------------------
// Generic fp32 GEMM: C[M,N] = A[M,K] @ B[N,K]^T (+bias) (+relu)
// 64x64 tile, 256 threads, 4x4 per thread. K % 16 == 0, N % 64 == 0.
// ---------------------------------------------------------------------------
template <bool RELU>
__global__ __launch_bounds__(256) void gemm_nt(
    const float* __restrict__ A, int lda,
    const float* __restrict__ B, int ldb,
    const float* __restrict__ bias,
    float* __restrict__ C, int ldc, int M, int N, int K)
{
    __shared__ __align__(16) float As[16][68];
    __shared__ __align__(16) float Bs[16][68];
    int m0 = blockIdx.y << 6, n0 = blockIdx.x << 6;
    int tid = threadIdx.x;
    int tx = tid & 15, ty = tid >> 4;
    int lm = tid >> 2, lk = (tid & 3) << 2;     // loader: row, k-offset
    float acc[4][4] = {{0.f}};

    for (int k0 = 0; k0 < K; k0 += 16) {
        float4 av;
        int gm = m0 + lm;
        if (gm < M) av = *(const float4*)(A + (size_t)gm * lda + k0 + lk);
        else        av = make_float4(0.f, 0.f, 0.f, 0.f);
        float4 bv = *(const float4*)(B + (size_t)(n0 + lm) * ldb + k0 + lk);
        As[lk + 0][lm] = av.x; As[lk + 1][lm] = av.y;
        As[lk + 2][lm] = av.z; As[lk + 3][lm] = av.w;
        Bs[lk + 0][lm] = bv.x; Bs[lk + 1][lm] = bv.y;
        Bs[lk + 2][lm] = bv.z; Bs[lk + 3][lm] = bv.w;
        __syncthreads();
#pragma unroll
        for (int kk = 0; kk < 16; ++kk) {
            float4 a = *(const float4*)&As[kk][ty << 2];
            float4 b = *(const float4*)&Bs[kk][tx << 2];
            acc[0][0] += a.x * b.x; acc[0][1] += a.x * b.y; acc[0][2] += a.x * b.z; acc[0][3] += a.x * b.w;
            acc[1][0] += a.y * b.x; acc[1][1] += a.y * b.y; acc[1][2] += a.y * b.z; acc[1][3] += a.y * b.w;
            acc[2][0] += a.z * b.x; acc[2][1] += a.z * b.y; acc[2][2] += a.z * b.z; acc[2][3] += a.z * b.w;
            acc[3][0] += a.w * b.x; acc[3][1] += a.w * b.y; acc[3][2] += a.w * b.z; acc[3][3] += a.w * b.w;
        }
        __syncthreads();
    }
#pragma unroll
    for (int i = 0; i < 4; ++i) {
        int gm = m0 + (ty << 2) + i;
        if (gm >= M) continue;
#pragma unroll
        for (int jj = 0; jj < 4; ++jj) {
            int gn = n0 + (tx << 2) + jj;
            float v = acc[i][jj];
            if (bias) v += bias[gn];
            if (RELU) v = fmaxf(v, 0.f);
            C[(size_t)gm * ldc + gn] = v;
        }
    }
}

// ---------------------------------------------------------------------------
// LayerNorm (in place): X[r] = LN(X[r] + res[map(r)]) * g + beta
// One block (256 thr) per row.
// ---------------------------------------------------------------------------
__global__ __launch_bounds__(256) void ln_kernel(
    float* __restrict__ X, const float* __restrict__ res,
    const int* __restrict__ map, const float* __restrict__ g,
    const float* __restrict__ beta)
{
    int r = blockIdx.x, j = threadIdx.x;
    __shared__ float red[8];
    float v = X[(size_t)r * DM + j];
    if (res) {
        int rr = map ? map[r] : r;
        v += res[(size_t)rr * DM + j];
    }
    float s = v;
#pragma unroll
    for (int o = 32; o; o >>= 1) s += __shfl_xor(s, o);
    if ((j & 63) == 0) red[j >> 6] = s;
    __syncthreads();
    float mean = (red[0] + red[1] + red[2] + red[3]) * (1.f / 256.f);
    float d = v - mean;
    float s2 = d * d;
#pragma unroll
    for (int o = 32; o; o >>= 1) s2 += __shfl_xor(s2, o);
    if ((j & 63) == 0) red[4 + (j >> 6)] = s2;
    __syncthreads();
    float var = (red[4] + red[5] + red[6] + red[7]) * (1.f / 256.f);
    float rstd = 1.f / sqrtf(var + 1e-5f);
    X[(size_t)r * DM + j] = d * rstd * g[j] + beta[j];
}

// ---------------------------------------------------------------------------
// K3a: layer-0 attention. Block per (t,b); for each head, stage K/V rows 0..t
// in LDS, waves split queries p<=t. Writes packed ao0 rows.
// ---------------------------------------------------------------------------
__global__ __launch_bounds__(256) void attn0_kernel(
    const float* __restrict__ qkv, float* __restrict__ ao)
{
    int tb = blockIdx.x;
    int t = tb >> 5, b = tb & 31;
    int tid = threadIdx.x;
    int w = tid >> 6, l = tid & 63;
    __shared__ float Kh[TS][65];
    __shared__ float Vh[TS][65];
    int tri = (t * (t + 1)) >> 1;

    for (int h = 0; h < NH; ++h) {
        for (int i = tid; i < (t + 1) * 64; i += 256) {
            int p = i >> 6, d = i & 63;
            size_t base = (size_t)(b * TS + p) * 768;
            Kh[p][d] = qkv[base + 256 + h * 64 + d];
            Vh[p][d] = qkv[base + 512 + h * 64 + d];
        }
        __syncthreads();
        for (int p = w; p <= t; p += 4) {
            float qv = qkv[(size_t)(b * TS + p) * 768 + h * 64 + l];
            float acc = 0.f;
#pragma unroll
            for (int d = 0; d < 64; ++d) acc += __shfl(qv, d) * Kh[l][d];
            float sc = (l <= t) ? acc * 0.125f : -1e30f;
            float m = sc;
#pragma unroll
            for (int o = 32; o; o >>= 1) m = fmaxf(m, __shfl_xor(m, o));
            float e = (l <= t) ? expf(sc - m) : 0.f;
            float ss = e;
#pragma unroll
            for (int o = 32; o; o >>= 1) ss += __shfl_xor(ss, o);
            float a = e / ss;
            float od = 0.f;
            for (int k = 0; k <= t; ++k) od += __shfl(a, k) * Vh[k][l];
            ao[((size_t)(tri + p) * 32 + b) * DM + h * 64 + l] = od;
        }
        __syncthreads();
    }
}

// ---------------------------------------------------------------------------
// K5: layer-1 attention. Block per (t,b): compute q = Wq @ h1[t,b,t] in-block,
// then attend over packed kv1 rows p<=t (2 heads staged at a time).
// ---------------------------------------------------------------------------
__global__ __launch_bounds__(256) void attn1_kernel(
    const float* __restrict__ h1, const float* __restrict__ kv1,
    const float* __restrict__ Wq, const float* __restrict__ bq,
    float* __restrict__ ao1)
{
    int tb = blockIdx.x;
    int t = tb >> 5, b = tb & 31;
    int tid = threadIdx.x;
    int w = tid >> 6, l = tid & 63;
    __shared__ float h1r[DM];
    __shared__ float q_l[DM];
    __shared__ float Ks[TS][131];
    __shared__ float Vs[TS][131];
    int tri = (t * (t + 1)) >> 1;

    h1r[tid] = h1[((size_t)(tri + t) * 32 + b) * DM + tid];
    __syncthreads();
    {
        float acc = bq[tid];
        const float4* w4 = (const float4*)(Wq + (size_t)tid * DM);
        for (int k4 = 0; k4 < 64; ++k4) {
            float4 ww = w4[k4];
            acc += ww.x * h1r[k4 * 4] + ww.y * h1r[k4 * 4 + 1] +
                   ww.z * h1r[k4 * 4 + 2] + ww.w * h1r[k4 * 4 + 3];
        }
        q_l[tid] = acc;
    }
    __syncthreads();

    for (int hp = 0; hp < 2; ++hp) {
        for (int i = tid; i < (t + 1) * 128; i += 256) {
            int p = i >> 7, d = i & 127;
            size_t row = (size_t)(tri + p) * 32 + b;
            Ks[p][d] = kv1[row * 512 + hp * 128 + d];
            Vs[p][d] = kv1[row * 512 + 256 + hp * 128 + d];
        }
        __syncthreads();
        if (w < 2) {
            int h = hp * 2 + w;
            float acc = 0.f;
            for (int d = 0; d < 64; ++d) acc += q_l[h * 64 + d] * Ks[l][w * 64 + d];
            float sc = (l <= t) ? acc * 0.125f : -1e30f;
            float m = sc;
#pragma unroll
            for (int o = 32; o; o >>= 1) m = fmaxf(m, __shfl_xor(m, o));
            float e = (l <= t) ? expf(sc - m) : 0.f;
            float ss = e;
#pragma unroll
            for (int o = 32; o; o >>= 1) ss += __shfl_xor(ss, o);
            float a = e / ss;
            float od = 0.f;
            for (int k = 0; k <= t; ++k) od += __shfl(a, k) * Vs[k][w * 64 + l];
            ao1[(size_t)tb * DM + h * 64 + l] = od;
        }
        __syncthreads();
    }
}

// ---------------------------------------------------------------------------
// K10: per (t,b): u = fus_w2^T @ cls_w[tok];  cpb = ctx@w1c^T + fus_b1;
//      s = fus_b2 . cls_w[tok] + cls_b[tok]
// ---------------------------------------------------------------------------
__global__ __launch_bounds__(256) void fuse_prep(
    const float* __restrict__ ctx, const int* __restrict__ tokens,
    const float* __restrict__ fw1, const float* __restrict__ fb1,
    const float* __restrict__ fw2, const float* __restrict__ fb2,
    const float* __restrict__ clsw, const float* __restrict__ clsb,
    float* __restrict__ cpb, float* __restrict__ u, float* __restrict__ sv)
{
    int tb = blockIdx.x;               // t*32+b, t in [0,40)
    int t = tb >> 5, b = tb & 31;
    int j = threadIdx.x;
    __shared__ float cw[DM];
    __shared__ float cr[DM];
    __shared__ float red[4];
    int tok = tokens[b * TS + t];
    cw[j] = clsw[(size_t)tok * DM + j];
    cr[j] = ctx[(size_t)tb * DM + j];
    __syncthreads();
    float uj = 0.f;
    for (int m = 0; m < DM; ++m) uj += fw2[m * DM + j] * cw[m];
    u[(size_t)tb * DM + j] = uj;
    float c = fb1[j];
    const float4* w1c = (const float4*)(fw1 + (size_t)j * (DINO + DM) + DINO);
    for (int d4 = 0; d4 < 64; ++d4) {
        float4 wv = w1c[d4];
        c += wv.x * cr[d4 * 4] + wv.y * cr[d4 * 4 + 1] +
             wv.z * cr[d4 * 4 + 2] + wv.w * cr[d4 * 4 + 3];
    }
    cpb[(size_t)tb * DM + j] = c;
    float s = fb2[j] * cw[j];
#pragma unroll
    for (int o = 32; o; o >>= 1) s += __shfl_xor(s, o);
    if ((j & 63) == 0) red[j >> 6] = s;
    __syncthreads();
    if (j == 0) sv[tb] = red[0] + red[1] + red[2] + red[3] + clsb[tok];
}

// ---------------------------------------------------------------------------
// K11: out[b,p,t] = sigmoid( sum_k gelu(pp[b,p,k]+cpb[t,b,k]) * u[t,b,k] + s[t,b] )
// ---------------------------------------------------------------------------
__global__ __launch_bounds__(256) void final_out(
    const float* __restrict__ pp, const float* __restrict__ cpb,
    const float* __restrict__ u, const float* __restrict__ sv,
    float* __restrict__ out)
{
    int bp = blockIdx.x;               // b*256+p
    int b = bp >> 8, p = bp & 255;
    int j = threadIdx.x;
    __shared__ float red[4];
    float ppj = pp[(size_t)bp * DM + j];
    for (int t = 0; t < TS; ++t) {
        int tb = t * 32 + b;
        float x = ppj + cpb[(size_t)tb * DM + j];
        float g = 0.5f * x * (1.f + erff(x * 0.70710678118654752440f));
        float val = g * u[(size_t)tb * DM + j];
#pragma unroll
        for (int o = 32; o; o >>= 1) val += __shfl_xor(val, o);
        if ((j & 63) == 0) red[j >> 6] = val;
        __syncthreads();
        if (j == 0) {
            float tot = red[0] + red[1] + red[2] + red[3] + sv[tb];
            out[(size_t)b * (NPATCH * TS) + p * TS + t] = 1.f / (1.f + expf(-tot));
        }
        __syncthreads();
    }
}

// ---------------------------------------------------------------------------
// Launcher
// ---------------------------------------------------------------------------
extern "C" void kernel_launch(void* const* d_in, const int* in_sizes, int n_in,
                              void* d_out, int out_size, void* d_ws, size_t ws_size,
                              hipStream_t stream)
{
    (void)in_sizes; (void)n_in; (void)out_size;
    const float* patches   = (const float*)d_in[0];
    const int*   tokens    = (const int*)  d_in[1];
    const float* embedding = (const float*)d_in[2];
    const float* pos_emb   = (const float*)d_in[3];
    const float* in_proj_w = (const float*)d_in[4];
    const float* in_proj_b = (const float*)d_in[5];
    const float* out_proj_w= (const float*)d_in[6];
    const float* out_proj_b= (const float*)d_in[7];
    const float* lin1_w    = (const float*)d_in[8];
    const float* lin1_b    = (const float*)d_in[9];
    const float* lin2_w    = (const float*)d_in[10];
    const float* lin2_b    = (const float*)d_in[11];
    const float* ln1_g     = (const float*)d_in[12];
    const float* ln1_b     = (const float*)d_in[13];
    const float* ln2_g     = (const float*)d_in[14];
    const float* ln2_b     = (const float*)d_in[15];
    const float* fus_w1    = (const float*)d_in[16];
    const float* fus_b1    = (const float*)d_in[17];
    const float* fus_w2    = (const float*)d_in[18];
    const float* fus_b2    = (const float*)d_in[19];
    const float* cls_w     = (const float*)d_in[20];
    const float* cls_b     = (const float*)d_in[21];

    if (ws_size < (size_t)WS_FLOATS * 4) return;   // refuse to corrupt memory

    float* ws   = (float*)d_ws;
    float* emb  = ws + OFF_EMB;
    float* qkv0 = ws + OFF_QKV0;
    float* x1   = ws + OFF_X1;
    float* h1   = ws + OFF_H1;
    float* big  = ws + OFF_BIG;       // ao0 / ff1-half / kv1 (sequential lifetimes)
    float* ao1  = ws + OFF_AO1;
    float* x2   = ws + OFF_X2;
    float* ff2  = ws + OFF_FF2;
    float* ctx  = ws + OFF_CTX;
    float* pp   = ws + OFF_PP;
    float* cpb  = ws + OFF_CPB;
    float* u    = ws + OFF_U;
    float* svec = ws + OFF_S;
    int*   map1 = (int*)(ws + OFF_MAP);
    int*   map2 = map1 + NTOK;

    // K0/K1: maps + embedding
    init_maps<<<98, 256, 0, stream>>>(map1, map2, ctx);
    embed_kernel<<<BB * TS, 256, 0, stream>>>(tokens, embedding, pos_emb, emb);

    // ---- Layer 0 ----
    // QKV (once per (b,p)): M=1280, N=768, K=256
    gemm_nt<false><<<dim3(12, 20), 256, 0, stream>>>(
        emb, DM, in_proj_w, DM, in_proj_b, qkv0, 768, BB * TS, 768, DM);
    // attention -> packed ao0
    attn0_kernel<<<NQ2, 256, 0, stream>>>(qkv0, big);
    // out-proj: x1 = ao0 @ Wout0^T + b ; then LN1 with emb residual
    gemm_nt<false><<<dim3(4, 390), 256, 0, stream>>>(
        big, DM, out_proj_w, DM, out_proj_b, x1, DM, NTOK, DM, DM);
    ln_kernel<<<NTOK, 256, 0, stream>>>(x1, emb, map1, ln1_g, ln1_b);
    // FF in two M-chunks (ff1 buffer aliases big region)
    for (int c = 0; c < 2; ++c) {
        float* xa = x1 + (size_t)c * 12480 * DM;
        float* ha = h1 + (size_t)c * 12480 * DM;
        gemm_nt<true><<<dim3(16, 195), 256, 0, stream>>>(
            xa, DM, lin1_w, DM, lin1_b, big, DFF, 12480, DFF, DM);
        gemm_nt<false><<<dim3(4, 195), 256, 0, stream>>>(
            big, DFF, lin2_w, DFF, lin2_b, ha, DM, 12480, DM, DFF);
    }
    ln_kernel<<<NTOK, 256, 0, stream>>>(h1, x1, nullptr, ln2_g, ln2_b);

    // ---- Layer 1 ----
    // K/V for all packed tokens: M=24960, N=512, K=256 (kv1 aliases big)
    gemm_nt<false><<<dim3(8, 390), 256, 0, stream>>>(
        h1, DM, in_proj_w + 768 * DM + 256 * DM, DM,
        in_proj_b + 768 + 256, big, 512, NTOK, 512, DM);
    // attention at query p=t (computes q in-block)
    attn1_kernel<<<NQ2, 256, 0, stream>>>(
        h1, big, in_proj_w + 768 * DM, in_proj_b + 768, ao1);
    // out-proj + LN1 (residual h1[t,b,t] via map2)
    gemm_nt<false><<<dim3(4, 20), 256, 0, stream>>>(
        ao1, DM, out_proj_w + DM * DM, DM, out_proj_b + DM, x2, DM, NQ2, DM, DM);
    ln_kernel<<<NQ2, 256, 0, stream>>>(x2, h1, map2, ln1_g + DM, ln1_b + DM);
    // FF + LN2 -> ctx rows 32..1279 (ctx row (t+1)*32+b)
    gemm_nt<true><<<dim3(16, 20), 256, 0, stream>>>(
        x2, DM, lin1_w + DFF * DM, DM, lin1_b + DFF, ff2, DFF, NQ2, DFF, DM);
    gemm_nt<false><<<dim3(4, 20), 256, 0, stream>>>(
        ff2, DFF, lin2_w + DM * DFF, DFF, lin2_b + DM, ctx + BB * DM, DM, NQ2, DM, DFF);
    ln_kernel<<<NQ2, 256, 0, stream>>>(ctx + BB * DM, x2, nullptr, ln2_g + DM, ln2_b + DM);

    // ---- Fusion head ----
    // pp = patches @ w1p^T : M=8192, N=256, K=384 (ldb=640)
    gemm_nt<false><<<dim3(4, 128), 256, 0, stream>>>(
        patches, DINO, fus_w1, DINO + DM, nullptr, pp, DM, BB * NPATCH, DM, DINO);
    // per-(t,b) u / cpb / s  (collapses the feat GEMM + logits dot)
    fuse_prep<<<TS * BB, 256, 0, stream>>>(
        ctx, tokens, fus_w1, fus_b1, fus_w2, fus_b2, cls_w, cls_b, cpb, u, svec);
    // final: gelu, dot with u, sigmoid, transpose to (b,p,t)
    final_out<<<BB * NPATCH, 256, 0, stream>>>(pp, cpb, u, svec, (float*)d_out);
}

// Round 2
// 1218.961 us; speedup vs baseline: 1.1204x; 1.1204x over previous
//
#include <hip/hip_runtime.h>
#include <math.h>

// ---------------------------------------------------------------------------
// Problem constants
// ---------------------------------------------------------------------------
#define DM    256     // D_MODEL
#define NH    4       // heads
#define HD    64      // head dim
#define TS    40      // T_SEQ
#define TM1   39
#define BB    32      // batch
#define DFF   1024
#define DINO  384
#define NPATCH 256
#define VOCAB 4096

#define NTOK  24960   // 780*32 packed (t, p<=t, b) tokens
#define NQ2   1248    // 39*32

// Packed row id: r = (tri(t)+p)*32 + b, tri(t)=t(t+1)/2

// ---------------------------------------------------------------------------
// Workspace layout (float offsets). "big" region aliases ao0 / ff1-half / kv1
// (their lifetimes are strictly sequential).
// ---------------------------------------------------------------------------
#define OFF_EMB   0u                      /* 1280*256    =   327680 */
#define OFF_QKV0  327680u                 /* 1280*768    =   983040 */
#define OFF_X1    1310720u                /* 24960*256   =  6389760 */
#define OFF_H1    7700480u                /* 24960*256   =  6389760 */
#define OFF_BIG   14090240u               /* max(ao0 6389760, ff1half 12779520, kv1 12779520) */
#define OFF_AO1   26869760u               /* 1248*256    =   319488 */
#define OFF_X2    27189248u               /* 1248*256    =   319488 */
#define OFF_FF2   27508736u               /* 1248*1024   =  1277952 */
#define OFF_CTX   28786688u               /* 40*32*256   =   327680 */
#define OFF_PP    29114368u               /* 8192*256    =  2097152 */
#define OFF_CPB   31211520u               /* 1280*256    =   327680 */
#define OFF_U     31539200u               /* 1280*256    =   327680 */
#define OFF_S     31866880u               /* 1280        */
#define OFF_MAP   31868160u               /* ints: map1 24960 + map2 1248 */
#define WS_FLOATS (31868160u + 26208u)

// ---------------------------------------------------------------------------
// K0: init row maps + zero ctx[t=0]
// ---------------------------------------------------------------------------
__global__ void init_maps(int* __restrict__ map1, int* __restrict__ map2,
                          float* __restrict__ ctx)
{
    int idx = blockIdx.x * 256 + threadIdx.x;
    if (idx < BB * DM) ctx[idx] = 0.f;                     // ctx rows for t=0
    if (idx < NQ2) {
        int t = idx >> 5, b = idx & 31;
        map2[idx] = ((t * (t + 1)) / 2 + t) * 32 + b;      // h1 row of (t,b,p=t)
    }
    if (idx < NTOK) {
        int q = idx >> 5, b = idx & 31;                    // q = tri(t)+p
        int t = 0;
        while (((t + 1) * (t + 2)) / 2 <= q) ++t;
        int p = q - (t * (t + 1)) / 2;
        map1[idx] = b * TS + p;                            // emb row of token
    }
}

// ---------------------------------------------------------------------------
// K1: emb[b,p,:] = embedding[tokens[b,p]] + pos_emb[p]
// ---------------------------------------------------------------------------
__global__ __launch_bounds__(256) void embed_kernel(
    const int* __restrict__ tokens, const float* __restrict__ etab,
    const float* __restrict__ pos, float* __restrict__ emb)
{
    int r = blockIdx.x;            // b*40+p
    int p = r % TS;
    int j = threadIdx.x;
    int tok = tokens[r];
    emb[(size_t)r * DM + j] = etab[(size_t)tok * DM + j] + pos[p * DM + j];
}

// ---------------------------------------------------------------------------
// Generic fp32 GEMM (small-M): C[M,N] = A[M,K] @ B[N,K]^T (+bias) (+relu)
// 64x64 tile, 256 threads, 4x4 per thread. K % 16 == 0, N % 64 == 0.
// ---------------------------------------------------------------------------
template <bool RELU>
__global__ __launch_bounds__(256) void gemm_nt(
    const float* __restrict__ A, int lda,
    const float* __restrict__ B, int ldb,
    const float* __restrict__ bias,
    float* __restrict__ C, int ldc, int M, int N, int K)
{
    __shared__ __align__(16) float As[16][68];
    __shared__ __align__(16) float Bs[16][68];
    int m0 = blockIdx.y << 6, n0 = blockIdx.x << 6;
    int tid = threadIdx.x;
    int tx = tid & 15, ty = tid >> 4;
    int lm = tid >> 2, lk = (tid & 3) << 2;     // loader: row, k-offset
    float acc[4][4] = {{0.f}};

    for (int k0 = 0; k0 < K; k0 += 16) {
        float4 av;
        int gm = m0 + lm;
        if (gm < M) av = *(const float4*)(A + (size_t)gm * lda + k0 + lk);
        else        av = make_float4(0.f, 0.f, 0.f, 0.f);
        float4 bv = *(const float4*)(B + (size_t)(n0 + lm) * ldb + k0 + lk);
        As[lk + 0][lm] = av.x; As[lk + 1][lm] = av.y;
        As[lk + 2][lm] = av.z; As[lk + 3][lm] = av.w;
        Bs[lk + 0][lm] = bv.x; Bs[lk + 1][lm] = bv.y;
        Bs[lk + 2][lm] = bv.z; Bs[lk + 3][lm] = bv.w;
        __syncthreads();
#pragma unroll
        for (int kk = 0; kk < 16; ++kk) {
            float4 a = *(const float4*)&As[kk][ty << 2];
            float4 b = *(const float4*)&Bs[kk][tx << 2];
            acc[0][0] += a.x * b.x; acc[0][1] += a.x * b.y; acc[0][2] += a.x * b.z; acc[0][3] += a.x * b.w;
            acc[1][0] += a.y * b.x; acc[1][1] += a.y * b.y; acc[1][2] += a.y * b.z; acc[1][3] += a.y * b.w;
            acc[2][0] += a.z * b.x; acc[2][1] += a.z * b.y; acc[2][2] += a.z * b.z; acc[2][3] += a.z * b.w;
            acc[3][0] += a.w * b.x; acc[3][1] += a.w * b.y; acc[3][2] += a.w * b.z; acc[3][3] += a.w * b.w;
        }
        __syncthreads();
    }
#pragma unroll
    for (int i = 0; i < 4; ++i) {
        int gm = m0 + (ty << 2) + i;
        if (gm >= M) continue;
#pragma unroll
        for (int jj = 0; jj < 4; ++jj) {
            int gn = n0 + (tx << 2) + jj;
            float v = acc[i][jj];
            if (bias) v += bias[gn];
            if (RELU) v = fmaxf(v, 0.f);
            C[(size_t)gm * ldc + gn] = v;
        }
    }
}

// ---------------------------------------------------------------------------
// Big fp32 GEMM: 128x128 tile, 256 threads, 8x8 per thread.
// C[M,N] = A[M,K] @ B[N,K]^T (+bias) (+relu). K%16==0, N%128==0, M-tail OK.
// Per k0-tile per wave: 1024 v_fma (2048 cyc) vs ~64 ds_read_b128 (~770 cyc)
// -> VALU-bound (~85%+).
// ---------------------------------------------------------------------------
template <bool RELU>
__global__ __launch_bounds__(256) void gemm_nt128(
    const float* __restrict__ A, int lda,
    const float* __restrict__ B, int ldb,
    const float* __restrict__ bias,
    float* __restrict__ C, int ldc, int M, int N, int K)
{
    __shared__ __align__(16) float As[16][132];
    __shared__ __align__(16) float Bs[16][132];
    int m0 = blockIdx.y << 7, n0 = blockIdx.x << 7;
    int tid = threadIdx.x;
    int tx = tid & 15, ty = tid >> 4;           // tx: n-frag, ty: m-frag
    int lr = tid >> 2;                          // loader row 0..63
    int lk = (tid & 3) << 2;                    // loader k offset 0,4,8,12
    float acc[8][8] = {{0.f}};

    for (int k0 = 0; k0 < K; k0 += 16) {
#pragma unroll
        for (int half = 0; half < 2; ++half) {
            int row = lr + half * 64;
            int gm = m0 + row;
            float4 av = (gm < M) ? *(const float4*)(A + (size_t)gm * lda + k0 + lk)
                                 : make_float4(0.f, 0.f, 0.f, 0.f);
            float4 bv = *(const float4*)(B + (size_t)(n0 + row) * ldb + k0 + lk);
            As[lk + 0][row] = av.x; As[lk + 1][row] = av.y;
            As[lk + 2][row] = av.z; As[lk + 3][row] = av.w;
            Bs[lk + 0][row] = bv.x; Bs[lk + 1][row] = bv.y;
            Bs[lk + 2][row] = bv.z; Bs[lk + 3][row] = bv.w;
        }
        __syncthreads();
#pragma unroll
        for (int kk = 0; kk < 16; ++kk) {
            float4 a0 = *(const float4*)&As[kk][ty * 8];
            float4 a1 = *(const float4*)&As[kk][ty * 8 + 4];
            float4 b0 = *(const float4*)&Bs[kk][tx * 8];
            float4 b1 = *(const float4*)&Bs[kk][tx * 8 + 4];
            float am[8] = {a0.x, a0.y, a0.z, a0.w, a1.x, a1.y, a1.z, a1.w};
            float bn[8] = {b0.x, b0.y, b0.z, b0.w, b1.x, b1.y, b1.z, b1.w};
#pragma unroll
            for (int i = 0; i < 8; ++i)
#pragma unroll
                for (int j = 0; j < 8; ++j)
                    acc[i][j] += am[i] * bn[j];
        }
        __syncthreads();
    }
#pragma unroll
    for (int i = 0; i < 8; ++i) {
        int gm = m0 + ty * 8 + i;
        if (gm >= M) continue;
        float4 o0, o1;
        float* po0 = &o0.x; float* po1 = &o1.x;
#pragma unroll
        for (int j = 0; j < 4; ++j) {
            int gn0 = n0 + tx * 8 + j;
            int gn1 = gn0 + 4;
            float v0 = acc[i][j]     + (bias ? bias[gn0] : 0.f);
            float v1 = acc[i][j + 4] + (bias ? bias[gn1] : 0.f);
            if (RELU) { v0 = fmaxf(v0, 0.f); v1 = fmaxf(v1, 0.f); }
            po0[j] = v0; po1[j] = v1;
        }
        *(float4*)(C + (size_t)gm * ldc + n0 + tx * 8)     = o0;
        *(float4*)(C + (size_t)gm * ldc + n0 + tx * 8 + 4) = o1;
    }
}

// ---------------------------------------------------------------------------
// LayerNorm (in place): X[r] = LN(X[r] + res[map(r)]) * g + beta
// One block (256 thr) per row.
// ---------------------------------------------------------------------------
__global__ __launch_bounds__(256) void ln_kernel(
    float* __restrict__ X, const float* __restrict__ res,
    const int* __restrict__ map, const float* __restrict__ g,
    const float* __restrict__ beta)
{
    int r = blockIdx.x, j = threadIdx.x;
    __shared__ float red[8];
    float v = X[(size_t)r * DM + j];
    if (res) {
        int rr = map ? map[r] : r;
        v += res[(size_t)rr * DM + j];
    }
    float s = v;
#pragma unroll
    for (int o = 32; o; o >>= 1) s += __shfl_xor(s, o);
    if ((j & 63) == 0) red[j >> 6] = s;
    __syncthreads();
    float mean = (red[0] + red[1] + red[2] + red[3]) * (1.f / 256.f);
    float d = v - mean;
    float s2 = d * d;
#pragma unroll
    for (int o = 32; o; o >>= 1) s2 += __shfl_xor(s2, o);
    if ((j & 63) == 0) red[4 + (j >> 6)] = s2;
    __syncthreads();
    float var = (red[4] + red[5] + red[6] + red[7]) * (1.f / 256.f);
    float rstd = 1.f / sqrtf(var + 1e-5f);
    X[(size_t)r * DM + j] = d * rstd * g[j] + beta[j];
}

// ---------------------------------------------------------------------------
// Layer-0 attention, online-softmax prefix form.
// Key insight: Q/K/V are copy-invariant; score s[p,k] is t-independent; the
// outputs for t = p..38 are an online-softmax prefix scan over keys.
// Block per (b,p): 4 waves = 4 heads, lane = head dim. No LDS, no syncs.
// ---------------------------------------------------------------------------
__global__ __launch_bounds__(256) void attn0_kernel(
    const float* __restrict__ qkv, float* __restrict__ ao)
{
    int bp = blockIdx.x;               // b*39 + p
    int b = bp / 39, p = bp % 39;
    int tid = threadIdx.x;
    int h = tid >> 6, l = tid & 63;

    // q for dim l (broadcast source for score phase)
    float qv = qkv[(size_t)(b * TS + p) * 768 + h * 64 + l];

    // scores: lane l holds s[key=l], keys 0..38 (lanes >=39 clamped, unused)
    int krow = (l < 39) ? l : 38;
    const float* Kr = qkv + (size_t)(b * TS + krow) * 768 + 256 + h * 64;
    float acc = 0.f;
#pragma unroll
    for (int d4 = 0; d4 < 16; ++d4) {
        float4 k4 = *(const float4*)(Kr + d4 * 4);
        acc += __shfl(qv, d4 * 4 + 0) * k4.x;
        acc += __shfl(qv, d4 * 4 + 1) * k4.y;
        acc += __shfl(qv, d4 * 4 + 2) * k4.z;
        acc += __shfl(qv, d4 * 4 + 3) * k4.w;
    }
    float s = acc * 0.125f;

    // online softmax over t = p..38, emitting one output row per t
    float m = -1e30f, lsum = 0.f, o = 0.f;
    for (int t = p; t < TM1; ++t) {
        float st = __shfl(s, t);
        float mnew = fmaxf(m, st);
        float c = __expf(m - mnew);
        float e = __expf(st - mnew);
        lsum = lsum * c + e;
        float vv = qkv[(size_t)(b * TS + t) * 768 + 512 + h * 64 + l];
        o = o * c + e * vv;
        m = mnew;
        int row = ((t * (t + 1)) >> 1) + p;
        ao[((size_t)row * 32 + b) * DM + h * 64 + l] = o / lsum;
    }
}

// ---------------------------------------------------------------------------
// K5: layer-1 attention. Block per (t,b): compute q = Wq @ h1[t,b,t] in-block,
// then attend over packed kv1 rows p<=t (2 heads staged at a time).
// ---------------------------------------------------------------------------
__global__ __launch_bounds__(256) void attn1_kernel(
    const float* __restrict__ h1, const float* __restrict__ kv1,
    const float* __restrict__ Wq, const float* __restrict__ bq,
    float* __restrict__ ao1)
{
    int tb = blockIdx.x;
    int t = tb >> 5, b = tb & 31;
    int tid = threadIdx.x;
    int w = tid >> 6, l = tid & 63;
    __shared__ float h1r[DM];
    __shared__ float q_l[DM];
    __shared__ float Ks[TS][131];
    __shared__ float Vs[TS][131];
    int tri = (t * (t + 1)) >> 1;

    h1r[tid] = h1[((size_t)(tri + t) * 32 + b) * DM + tid];
    __syncthreads();
    {
        float acc = bq[tid];
        const float4* w4 = (const float4*)(Wq + (size_t)tid * DM);
        for (int k4 = 0; k4 < 64; ++k4) {
            float4 ww = w4[k4];
            acc += ww.x * h1r[k4 * 4] + ww.y * h1r[k4 * 4 + 1] +
                   ww.z * h1r[k4 * 4 + 2] + ww.w * h1r[k4 * 4 + 3];
        }
        q_l[tid] = acc;
    }
    __syncthreads();

    for (int hp = 0; hp < 2; ++hp) {
        for (int i = tid; i < (t + 1) * 128; i += 256) {
            int p = i >> 7, d = i & 127;
            size_t row = (size_t)(tri + p) * 32 + b;
            Ks[p][d] = kv1[row * 512 + hp * 128 + d];
            Vs[p][d] = kv1[row * 512 + 256 + hp * 128 + d];
        }
        __syncthreads();
        if (w < 2) {
            int h = hp * 2 + w;
            float acc = 0.f;
            for (int d = 0; d < 64; ++d) acc += q_l[h * 64 + d] * Ks[l][w * 64 + d];
            float sc = (l <= t) ? acc * 0.125f : -1e30f;
            float m = sc;
#pragma unroll
            for (int o = 32; o; o >>= 1) m = fmaxf(m, __shfl_xor(m, o));
            float e = (l <= t) ? expf(sc - m) : 0.f;
            float ss = e;
#pragma unroll
            for (int o = 32; o; o >>= 1) ss += __shfl_xor(ss, o);
            float a = e / ss;
            float od = 0.f;
            for (int k = 0; k <= t; ++k) od += __shfl(a, k) * Vs[k][w * 64 + l];
            ao1[(size_t)tb * DM + h * 64 + l] = od;
        }
        __syncthreads();
    }
}

// ---------------------------------------------------------------------------
// K10: per (t,b): u = fus_w2^T @ cls_w[tok];  cpb = ctx@w1c^T + fus_b1;
//      s = fus_b2 . cls_w[tok] + cls_b[tok]
// ---------------------------------------------------------------------------
__global__ __launch_bounds__(256) void fuse_prep(
    const float* __restrict__ ctx, const int* __restrict__ tokens,
    const float* __restrict__ fw1, const float* __restrict__ fb1,
    const float* __restrict__ fw2, const float* __restrict__ fb2,
    const float* __restrict__ clsw, const float* __restrict__ clsb,
    float* __restrict__ cpb, float* __restrict__ u, float* __restrict__ sv)
{
    int tb = blockIdx.x;               // t*32+b, t in [0,40)
    int t = tb >> 5, b = tb & 31;
    int j = threadIdx.x;
    __shared__ float cw[DM];
    __shared__ float cr[DM];
    __shared__ float red[4];
    int tok = tokens[b * TS + t];
    cw[j] = clsw[(size_t)tok * DM + j];
    cr[j] = ctx[(size_t)tb * DM + j];
    __syncthreads();
    float uj = 0.f;
    for (int m = 0; m < DM; ++m) uj += fw2[m * DM + j] * cw[m];
    u[(size_t)tb * DM + j] = uj;
    float c = fb1[j];
    const float4* w1c = (const float4*)(fw1 + (size_t)j * (DINO + DM) + DINO);
    for (int d4 = 0; d4 < 64; ++d4) {
        float4 wv = w1c[d4];
        c += wv.x * cr[d4 * 4] + wv.y * cr[d4 * 4 + 1] +
             wv.z * cr[d4 * 4 + 2] + wv.w * cr[d4 * 4 + 3];
    }
    cpb[(size_t)tb * DM + j] = c;
    float s = fb2[j] * cw[j];
#pragma unroll
    for (int o = 32; o; o >>= 1) s += __shfl_xor(s, o);
    if ((j & 63) == 0) red[j >> 6] = s;
    __syncthreads();
    if (j == 0) sv[tb] = red[0] + red[1] + red[2] + red[3] + clsb[tok];
}

// ---------------------------------------------------------------------------
// K11: out[b,p,t] = sigmoid( sum_k gelu(pp[b,p,k]+cpb[t,b,k]) * u[t,b,k] + s[t,b] )
// Block per (b,p); wave w handles t = w, w+4, ...; lane covers 4 k-chunks.
// No LDS, no block syncs; pp cached in registers.
// ---------------------------------------------------------------------------
__global__ __launch_bounds__(256) void final_out(
    const float* __restrict__ pp, const float* __restrict__ cpb,
    const float* __restrict__ u, const float* __restrict__ sv,
    float* __restrict__ out)
{
    int bp = blockIdx.x;               // b*256+p
    int b = bp >> 8;
    int tid = threadIdx.x;
    int w = tid >> 6, l = tid & 63;
    const float* ppr = pp + (size_t)bp * DM;
    float p0 = ppr[l], p1 = ppr[64 + l], p2 = ppr[128 + l], p3 = ppr[192 + l];
    const float k2 = 0.70710678118654752440f;
    for (int t = w; t < TS; t += 4) {
        int tb = t * 32 + b;
        const float* cp = cpb + (size_t)tb * DM;
        const float* uu = u + (size_t)tb * DM;
        float x, v;
        x = p0 + cp[l];       v  = 0.5f * x * (1.f + erff(x * k2)) * uu[l];
        x = p1 + cp[64 + l];  v += 0.5f * x * (1.f + erff(x * k2)) * uu[64 + l];
        x = p2 + cp[128 + l]; v += 0.5f * x * (1.f + erff(x * k2)) * uu[128 + l];
        x = p3 + cp[192 + l]; v += 0.5f * x * (1.f + erff(x * k2)) * uu[192 + l];
#pragma unroll
        for (int off = 32; off; off >>= 1) v += __shfl_xor(v, off);
        if (l == 0) out[(size_t)bp * TS + t] = 1.f / (1.f + expf(-(v + sv[tb])));
    }
}

// ---------------------------------------------------------------------------
// Launcher
// ---------------------------------------------------------------------------
extern "C" void kernel_launch(void* const* d_in, const int* in_sizes, int n_in,
                              void* d_out, int out_size, void* d_ws, size_t ws_size,
                              hipStream_t stream)
{
    (void)in_sizes; (void)n_in; (void)out_size;
    const float* patches   = (const float*)d_in[0];
    const int*   tokens    = (const int*)  d_in[1];
    const float* embedding = (const float*)d_in[2];
    const float* pos_emb   = (const float*)d_in[3];
    const float* in_proj_w = (const float*)d_in[4];
    const float* in_proj_b = (const float*)d_in[5];
    const float* out_proj_w= (const float*)d_in[6];
    const float* out_proj_b= (const float*)d_in[7];
    const float* lin1_w    = (const float*)d_in[8];
    const float* lin1_b    = (const float*)d_in[9];
    const float* lin2_w    = (const float*)d_in[10];
    const float* lin2_b    = (const float*)d_in[11];
    const float* ln1_g     = (const float*)d_in[12];
    const float* ln1_b     = (const float*)d_in[13];
    const float* ln2_g     = (const float*)d_in[14];
    const float* ln2_b     = (const float*)d_in[15];
    const float* fus_w1    = (const float*)d_in[16];
    const float* fus_b1    = (const float*)d_in[17];
    const float* fus_w2    = (const float*)d_in[18];
    const float* fus_b2    = (const float*)d_in[19];
    const float* cls_w     = (const float*)d_in[20];
    const float* cls_b     = (const float*)d_in[21];

    if (ws_size < (size_t)WS_FLOATS * 4) return;   // refuse to corrupt memory

    float* ws   = (float*)d_ws;
    float* emb  = ws + OFF_EMB;
    float* qkv0 = ws + OFF_QKV0;
    float* x1   = ws + OFF_X1;
    float* h1   = ws + OFF_H1;
    float* big  = ws + OFF_BIG;       // ao0 / ff1-half / kv1 (sequential lifetimes)
    float* ao1  = ws + OFF_AO1;
    float* x2   = ws + OFF_X2;
    float* ff2  = ws + OFF_FF2;
    float* ctx  = ws + OFF_CTX;
    float* pp   = ws + OFF_PP;
    float* cpb  = ws + OFF_CPB;
    float* u    = ws + OFF_U;
    float* svec = ws + OFF_S;
    int*   map1 = (int*)(ws + OFF_MAP);
    int*   map2 = map1 + NTOK;

    // K0/K1: maps + embedding
    init_maps<<<98, 256, 0, stream>>>(map1, map2, ctx);
    embed_kernel<<<BB * TS, 256, 0, stream>>>(tokens, embedding, pos_emb, emb);

    // ---- Layer 0 ----
    // QKV (once per (b,p)): M=1280, N=768, K=256
    gemm_nt<false><<<dim3(12, 20), 256, 0, stream>>>(
        emb, DM, in_proj_w, DM, in_proj_b, qkv0, 768, BB * TS, 768, DM);
    // attention -> packed ao0 (online-softmax prefix scan over t)
    attn0_kernel<<<NQ2, 256, 0, stream>>>(qkv0, big);
    // out-proj: x1 = ao0 @ Wout0^T + b ; then LN1 with emb residual
    gemm_nt128<false><<<dim3(2, 195), 256, 0, stream>>>(
        big, DM, out_proj_w, DM, out_proj_b, x1, DM, NTOK, DM, DM);
    ln_kernel<<<NTOK, 256, 0, stream>>>(x1, emb, map1, ln1_g, ln1_b);
    // FF in two M-chunks (ff1 buffer aliases big region)
    for (int c = 0; c < 2; ++c) {
        float* xa = x1 + (size_t)c * 12480 * DM;
        float* ha = h1 + (size_t)c * 12480 * DM;
        gemm_nt128<true><<<dim3(8, 98), 256, 0, stream>>>(
            xa, DM, lin1_w, DM, lin1_b, big, DFF, 12480, DFF, DM);
        gemm_nt128<false><<<dim3(2, 98), 256, 0, stream>>>(
            big, DFF, lin2_w, DFF, lin2_b, ha, DM, 12480, DM, DFF);
    }
    ln_kernel<<<NTOK, 256, 0, stream>>>(h1, x1, nullptr, ln2_g, ln2_b);

    // ---- Layer 1 ----
    // K/V for all packed tokens: M=24960, N=512, K=256 (kv1 aliases big)
    gemm_nt128<false><<<dim3(4, 195), 256, 0, stream>>>(
        h1, DM, in_proj_w + 768 * DM + 256 * DM, DM,
        in_proj_b + 768 + 256, big, 512, NTOK, 512, DM);
    // attention at query p=t (computes q in-block)
    attn1_kernel<<<NQ2, 256, 0, stream>>>(
        h1, big, in_proj_w + 768 * DM, in_proj_b + 768, ao1);
    // out-proj + LN1 (residual h1[t,b,t] via map2)
    gemm_nt<false><<<dim3(4, 20), 256, 0, stream>>>(
        ao1, DM, out_proj_w + DM * DM, DM, out_proj_b + DM, x2, DM, NQ2, DM, DM);
    ln_kernel<<<NQ2, 256, 0, stream>>>(x2, h1, map2, ln1_g + DM, ln1_b + DM);
    // FF + LN2 -> ctx rows 32..1279 (ctx row (t+1)*32+b)
    gemm_nt<true><<<dim3(16, 20), 256, 0, stream>>>(
        x2, DM, lin1_w + DFF * DM, DM, lin1_b + DFF, ff2, DFF, NQ2, DFF, DM);
    gemm_nt<false><<<dim3(4, 20), 256, 0, stream>>>(
        ff2, DFF, lin2_w + DM * DFF, DFF, lin2_b + DM, ctx + BB * DM, DM, NQ2, DM, DFF);
    ln_kernel<<<NQ2, 256, 0, stream>>>(ctx + BB * DM, x2, nullptr, ln2_g + DM, ln2_b + DM);

    // ---- Fusion head ----
    // pp = patches @ w1p^T : M=8192, N=256, K=384 (ldb=640)
    gemm_nt128<false><<<dim3(2, 64), 256, 0, stream>>>(
        patches, DINO, fus_w1, DINO + DM, nullptr, pp, DM, BB * NPATCH, DM, DINO);
    // per-(t,b) u / cpb / s  (collapses the feat GEMM + logits dot)
    fuse_prep<<<TS * BB, 256, 0, stream>>>(
        ctx, tokens, fus_w1, fus_b1, fus_w2, fus_b2, cls_w, cls_b, cpb, u, svec);
    // final: gelu, dot with u, sigmoid, transpose to (b,p,t)
    final_out<<<BB * NPATCH, 256, 0, stream>>>(pp, cpb, u, svec, (float*)d_out);
}

// Round 5
// 797.027 us; speedup vs baseline: 1.7135x; 1.5294x over previous
//
#include <hip/hip_runtime.h>
#include <math.h>

// ---------------------------------------------------------------------------
// Problem constants
// ---------------------------------------------------------------------------
#define DM    256     // D_MODEL
#define NH    4
#define HD    64
#define TS    40
#define TM1   39
#define BB    32
#define DFF   1024
#define DINO  384
#define NPATCH 256
#define VOCAB 4096

#define NTOK  24960   // 780*32 packed (t, p<=t, b) tokens
#define NQ2   1248    // 39*32

typedef _Float16 f16;
typedef __attribute__((ext_vector_type(8))) _Float16 half8;  // MFMA A/B frag
typedef __attribute__((ext_vector_type(4))) float f32x4;

// ---------------------------------------------------------------------------
// Workspace layout (float offsets) — identical to the PASSED round-2 layout.
// All activations fp32. big aliases ao0 / ff1-chunk / kv1 (sequential lives).
// ---------------------------------------------------------------------------
#define OFF_EMB   0u                      /* 1280*256    =   327680 */
#define OFF_QKV0  327680u                 /* 1280*768    =   983040 */
#define OFF_X1    1310720u                /* 24960*256   =  6389760 */
#define OFF_H1    7700480u                /* 24960*256   =  6389760 */
#define OFF_BIG   14090240u               /* 12779520: ao0(6.4M)/ff1chunk(8.5M)/kv1(12.78M) */
#define OFF_AO1   26869760u               /* 1248*256    =   319488 */
#define OFF_X2    27189248u               /* 1248*256    =   319488 */
#define OFF_FF2   27508736u               /* 1248*1024   =  1277952 */
#define OFF_CTX   28786688u               /* 40*32*256   =   327680 */
#define OFF_PP    29114368u               /* 8192*256    =  2097152 */
#define OFF_CPB   31211520u               /* 1280*256    =   327680 */
#define OFF_U     31539200u               /* 1280*256    =   327680 */
#define OFF_S     31866880u               /* 1280        */
#define OFF_MAP   31868160u               /* ints: map1 24960 + map2 1248 */
#define WS_FLOATS (31868160u + 26208u)

// ---------------------------------------------------------------------------
// K0: init row maps + zero ctx[t=0]
// ---------------------------------------------------------------------------
__global__ void init_maps(int* __restrict__ map1, int* __restrict__ map2,
                          float* __restrict__ ctx)
{
    int idx = blockIdx.x * 256 + threadIdx.x;
    if (idx < BB * DM) ctx[idx] = 0.f;
    if (idx < NQ2) {
        int t = idx >> 5, b = idx & 31;
        map2[idx] = ((t * (t + 1)) / 2 + t) * 32 + b;      // packed row of (t,b,p=t)
    }
    if (idx < NTOK) {
        int q = idx >> 5, b = idx & 31;                    // q = tri(t)+p
        int t = 0;
        while (((t + 1) * (t + 2)) / 2 <= q) ++t;
        int p = q - (t * (t + 1)) / 2;
        map1[idx] = b * TS + p;                            // emb row of token
    }
}

// ---------------------------------------------------------------------------
// K1: emb[b,p,:] = embedding[tokens[b,p]] + pos_emb[p]   (fp32)
// ---------------------------------------------------------------------------
__global__ __launch_bounds__(256) void embed_kernel(
    const int* __restrict__ tokens, const float* __restrict__ etab,
    const float* __restrict__ pos, float* __restrict__ emb)
{
    int r = blockIdx.x;            // b*40+p
    int p = r % TS;
    int j = threadIdx.x;
    int tok = tokens[r];
    emb[(size_t)r * DM + j] = etab[(size_t)tok * DM + j] + pos[p * DM + j];
}

// ---------------------------------------------------------------------------
// fp32 GEMM (small M, M-tail OK): C[M,N] = A[M,K] @ B[N,K]^T (+bias)(+relu)
// 64x64 tile, 256 threads, 4x4/thread. K%16==0, N%64==0.
// (kept for the layer-1 small GEMMs, M=1248)
// ---------------------------------------------------------------------------
template <bool RELU>
__global__ __launch_bounds__(256) void gemm_nt(
    const float* __restrict__ A, int lda,
    const float* __restrict__ B, int ldb,
    const float* __restrict__ bias,
    float* __restrict__ C, int ldc, int M, int N, int K)
{
    __shared__ __align__(16) float As[16][68];
    __shared__ __align__(16) float Bs[16][68];
    int m0 = blockIdx.y << 6, n0 = blockIdx.x << 6;
    int tid = threadIdx.x;
    int tx = tid & 15, ty = tid >> 4;
    int lm = tid >> 2, lk = (tid & 3) << 2;
    float acc[4][4] = {{0.f}};

    for (int k0 = 0; k0 < K; k0 += 16) {
        float4 av;
        int gm = m0 + lm;
        if (gm < M) av = *(const float4*)(A + (size_t)gm * lda + k0 + lk);
        else        av = make_float4(0.f, 0.f, 0.f, 0.f);
        float4 bv = *(const float4*)(B + (size_t)(n0 + lm) * ldb + k0 + lk);
        As[lk + 0][lm] = av.x; As[lk + 1][lm] = av.y;
        As[lk + 2][lm] = av.z; As[lk + 3][lm] = av.w;
        Bs[lk + 0][lm] = bv.x; Bs[lk + 1][lm] = bv.y;
        Bs[lk + 2][lm] = bv.z; Bs[lk + 3][lm] = bv.w;
        __syncthreads();
#pragma unroll
        for (int kk = 0; kk < 16; ++kk) {
            float4 a = *(const float4*)&As[kk][ty << 2];
            float4 b = *(const float4*)&Bs[kk][tx << 2];
            acc[0][0] += a.x * b.x; acc[0][1] += a.x * b.y; acc[0][2] += a.x * b.z; acc[0][3] += a.x * b.w;
            acc[1][0] += a.y * b.x; acc[1][1] += a.y * b.y; acc[1][2] += a.y * b.z; acc[1][3] += a.y * b.w;
            acc[2][0] += a.z * b.x; acc[2][1] += a.z * b.y; acc[2][2] += a.z * b.z; acc[2][3] += a.z * b.w;
            acc[3][0] += a.w * b.x; acc[3][1] += a.w * b.y; acc[3][2] += a.w * b.z; acc[3][3] += a.w * b.w;
        }
        __syncthreads();
    }
#pragma unroll
    for (int i = 0; i < 4; ++i) {
        int gm = m0 + (ty << 2) + i;
        if (gm >= M) continue;
#pragma unroll
        for (int jj = 0; jj < 4; ++jj) {
            int gn = n0 + (tx << 2) + jj;
            float v = acc[i][jj];
            if (bias) v += bias[gn];
            if (RELU) v = fmaxf(v, 0.f);
            C[(size_t)gm * ldc + gn] = v;
        }
    }
}

// ---------------------------------------------------------------------------
// MFMA GEMM with fp32 interface: C[M,N] = A[M,K] @ B[N,K]^T (+bias)(+relu).
// A,B are fp32 in global; converted to fp16 in registers during LDS staging;
// fp32 accumulate; fp32 store. NO 16-bit storage of any tensor -> numerics
// are round-2 plus only the transient GEMM-input quantization (rel 2^-11).
// 128x128 tile, 4 waves (2x2), each 64x64 via 4x4 MFMA 16x16x32_f16.
// Requirements: M%128==0, N%128==0, K%64==0, fp32 rows 16B-aligned.
// LDS fragment-ordered (lane l <-> row l&15, k-quad l>>4): conflict-free
// ds_read_b128; any consistent lane->k bijection used for BOTH A and B
// yields the correct product (permutation-proof), C/D map m89-verified.
// ---------------------------------------------------------------------------
template <bool RELU>
__global__ __launch_bounds__(256) void gemm_mf(
    const float* __restrict__ A, int lda,
    const float* __restrict__ B, int ldb,
    const float* __restrict__ bias,
    float* __restrict__ C, int ldc, int K)
{
    __shared__ __align__(16) f16 lds[32 * 512];   // 32 frags x 512 halves = 32 KB
    int tid = threadIdx.x;
    int w = tid >> 6, l = tid & 63;
    int m0 = blockIdx.y << 7, n0 = blockIdx.x << 7;
    int lrow = l & 15;              // m (or n) within fragment
    int lk8  = (l >> 4) << 3;       // k offset within 32-chunk: 0,8,16,24
    int wm = w >> 1, wn = w & 1;

    f32x4 acc[4][4] = {};

    for (int k0 = 0; k0 < K; k0 += 64) {
        // stage: wave w fills A-frags 4w..4w+3 and the matching B-frags
#pragma unroll
        for (int j = 0; j < 4; ++j) {
            int f  = (w << 2) + j;         // 0..15
            int mi = f >> 1, kc = f & 1;
            const float* ga = A + (size_t)(m0 + (mi << 4) + lrow) * lda + k0 + (kc << 5) + lk8;
            const float* gb = B + (size_t)(n0 + (mi << 4) + lrow) * ldb + k0 + (kc << 5) + lk8;
            float4 a0 = *(const float4*)ga, a1 = *(const float4*)(ga + 4);
            float4 b0 = *(const float4*)gb, b1 = *(const float4*)(gb + 4);
            half8 ha, hb;
            ha[0] = (f16)a0.x; ha[1] = (f16)a0.y; ha[2] = (f16)a0.z; ha[3] = (f16)a0.w;
            ha[4] = (f16)a1.x; ha[5] = (f16)a1.y; ha[6] = (f16)a1.z; ha[7] = (f16)a1.w;
            hb[0] = (f16)b0.x; hb[1] = (f16)b0.y; hb[2] = (f16)b0.z; hb[3] = (f16)b0.w;
            hb[4] = (f16)b1.x; hb[5] = (f16)b1.y; hb[6] = (f16)b1.z; hb[7] = (f16)b1.w;
            *(half8*)&lds[(f << 9) + (l << 3)]        = ha;
            *(half8*)&lds[((f + 16) << 9) + (l << 3)] = hb;
        }
        __syncthreads();
#pragma unroll
        for (int kc = 0; kc < 2; ++kc) {
            half8 af[4], bfr[4];
#pragma unroll
            for (int i = 0; i < 4; ++i) {
                int mi = (wm << 2) + i;
                int nj = (wn << 2) + i;
                af[i]  = *(half8*)&lds[(((mi << 1) | kc) << 9) + (l << 3)];
                bfr[i] = *(half8*)&lds[((16 + ((nj << 1) | kc)) << 9) + (l << 3)];
            }
#pragma unroll
            for (int i = 0; i < 4; ++i)
#pragma unroll
                for (int j2 = 0; j2 < 4; ++j2)
                    acc[i][j2] = __builtin_amdgcn_mfma_f32_16x16x32_f16(
                        af[i], bfr[j2], acc[i][j2], 0, 0, 0);
        }
        __syncthreads();
    }

    // epilogue: D col = lane&15, row = (lane>>4)*4 + reg   [m89/m91 verified]
    int colq = l & 15, rowq = (l >> 4) << 2;
#pragma unroll
    for (int i = 0; i < 4; ++i) {
        int gmb = m0 + (wm << 6) + (i << 4) + rowq;
#pragma unroll
        for (int j2 = 0; j2 < 4; ++j2) {
            int gn = n0 + (wn << 6) + (j2 << 4) + colq;
            float bv = bias ? bias[gn] : 0.f;
#pragma unroll
            for (int r = 0; r < 4; ++r) {
                float v = acc[i][j2][r] + bv;
                if (RELU) v = fmaxf(v, 0.f);
                C[(size_t)(gmb + r) * ldc + gn] = v;
            }
        }
    }
}

// ---------------------------------------------------------------------------
// LayerNorm (in place, fp32): X[r] = LN(X[r] + res[map(r)]) * g + beta
// ---------------------------------------------------------------------------
__global__ __launch_bounds__(256) void ln_kernel(
    float* __restrict__ X, const float* __restrict__ res,
    const int* __restrict__ map, const float* __restrict__ g,
    const float* __restrict__ beta)
{
    int r = blockIdx.x, j = threadIdx.x;
    __shared__ float red[8];
    float v = X[(size_t)r * DM + j];
    if (res) {
        int rr = map ? map[r] : r;
        v += res[(size_t)rr * DM + j];
    }
    float s = v;
#pragma unroll
    for (int o = 32; o; o >>= 1) s += __shfl_xor(s, o);
    if ((j & 63) == 0) red[j >> 6] = s;
    __syncthreads();
    float mean = (red[0] + red[1] + red[2] + red[3]) * (1.f / 256.f);
    float d = v - mean;
    float s2 = d * d;
#pragma unroll
    for (int o = 32; o; o >>= 1) s2 += __shfl_xor(s2, o);
    if ((j & 63) == 0) red[4 + (j >> 6)] = s2;
    __syncthreads();
    float var = (red[4] + red[5] + red[6] + red[7]) * (1.f / 256.f);
    float rstd = 1.f / sqrtf(var + 1e-5f);
    X[(size_t)r * DM + j] = d * rstd * g[j] + beta[j];
}

// ---------------------------------------------------------------------------
// Layer-0 attention, online-softmax prefix form (fp32 in/out, as round 2).
// Block per (b,p): 4 waves = 4 heads, lane = head dim. No LDS, no syncs.
// ---------------------------------------------------------------------------
__global__ __launch_bounds__(256) void attn0_kernel(
    const float* __restrict__ qkv, float* __restrict__ ao)
{
    int bp = blockIdx.x;               // b*39 + p
    int b = bp / 39, p = bp % 39;
    int tid = threadIdx.x;
    int h = tid >> 6, l = tid & 63;

    float qv = qkv[(size_t)(b * TS + p) * 768 + h * 64 + l];

    int krow = (l < 39) ? l : 38;
    const float* Kr = qkv + (size_t)(b * TS + krow) * 768 + 256 + h * 64;
    float acc = 0.f;
#pragma unroll
    for (int d4 = 0; d4 < 16; ++d4) {
        float4 k4 = *(const float4*)(Kr + d4 * 4);
        acc += __shfl(qv, d4 * 4 + 0) * k4.x;
        acc += __shfl(qv, d4 * 4 + 1) * k4.y;
        acc += __shfl(qv, d4 * 4 + 2) * k4.z;
        acc += __shfl(qv, d4 * 4 + 3) * k4.w;
    }
    float s = acc * 0.125f;

    float m = -1e30f, lsum = 0.f, o = 0.f;
    for (int t = p; t < TM1; ++t) {
        float st = __shfl(s, t);
        float mnew = fmaxf(m, st);
        float c = __expf(m - mnew);
        float e = __expf(st - mnew);
        lsum = lsum * c + e;
        float vv = qkv[(size_t)(b * TS + t) * 768 + 512 + h * 64 + l];
        o = o * c + e * vv;
        m = mnew;
        int row = ((t * (t + 1)) >> 1) + p;
        ao[((size_t)row * 32 + b) * DM + h * 64 + l] = o / lsum;
    }
}

// ---------------------------------------------------------------------------
// Layer-1 attention (fp32, as round 2). Block per (t,b).
// ---------------------------------------------------------------------------
__global__ __launch_bounds__(256) void attn1_kernel(
    const float* __restrict__ h1, const float* __restrict__ kv1,
    const float* __restrict__ Wq, const float* __restrict__ bq,
    float* __restrict__ ao1)
{
    int tb = blockIdx.x;
    int t = tb >> 5, b = tb & 31;
    int tid = threadIdx.x;
    int w = tid >> 6, l = tid & 63;
    __shared__ float h1r[DM];
    __shared__ float q_l[DM];
    __shared__ float Ks[TS][131];
    __shared__ float Vs[TS][131];
    int tri = (t * (t + 1)) >> 1;

    h1r[tid] = h1[((size_t)(tri + t) * 32 + b) * DM + tid];
    __syncthreads();
    {
        float acc = bq[tid];
        const float4* w4 = (const float4*)(Wq + (size_t)tid * DM);
        for (int k4 = 0; k4 < 64; ++k4) {
            float4 ww = w4[k4];
            acc += ww.x * h1r[k4 * 4] + ww.y * h1r[k4 * 4 + 1] +
                   ww.z * h1r[k4 * 4 + 2] + ww.w * h1r[k4 * 4 + 3];
        }
        q_l[tid] = acc;
    }
    __syncthreads();

    for (int hp = 0; hp < 2; ++hp) {
        for (int i = tid; i < (t + 1) * 128; i += 256) {
            int p = i >> 7, d = i & 127;
            size_t row = (size_t)(tri + p) * 32 + b;
            Ks[p][d] = kv1[row * 512 + hp * 128 + d];
            Vs[p][d] = kv1[row * 512 + 256 + hp * 128 + d];
        }
        __syncthreads();
        if (w < 2) {
            int h = hp * 2 + w;
            float acc = 0.f;
            for (int d = 0; d < 64; ++d) acc += q_l[h * 64 + d] * Ks[l][w * 64 + d];
            float sc = (l <= t) ? acc * 0.125f : -1e30f;
            float m = sc;
#pragma unroll
            for (int o = 32; o; o >>= 1) m = fmaxf(m, __shfl_xor(m, o));
            float e = (l <= t) ? expf(sc - m) : 0.f;
            float ss = e;
#pragma unroll
            for (int o = 32; o; o >>= 1) ss += __shfl_xor(ss, o);
            float a = e / ss;
            float od = 0.f;
            for (int k = 0; k <= t; ++k) od += __shfl(a, k) * Vs[k][w * 64 + l];
            ao1[(size_t)tb * DM + h * 64 + l] = od;
        }
        __syncthreads();
    }
}

// ---------------------------------------------------------------------------
// per (t,b): u = fus_w2^T @ cls_w[tok]; cpb = ctx@w1c^T + fus_b1;
//            s = fus_b2 . cls_w[tok] + cls_b[tok]
// ---------------------------------------------------------------------------
__global__ __launch_bounds__(256) void fuse_prep(
    const float* __restrict__ ctx, const int* __restrict__ tokens,
    const float* __restrict__ fw1, const float* __restrict__ fb1,
    const float* __restrict__ fw2, const float* __restrict__ fb2,
    const float* __restrict__ clsw, const float* __restrict__ clsb,
    float* __restrict__ cpb, float* __restrict__ u, float* __restrict__ sv)
{
    int tb = blockIdx.x;               // t*32+b
    int t = tb >> 5, b = tb & 31;
    int j = threadIdx.x;
    __shared__ float cw[DM];
    __shared__ float cr[DM];
    __shared__ float red[4];
    int tok = tokens[b * TS + t];
    cw[j] = clsw[(size_t)tok * DM + j];
    cr[j] = ctx[(size_t)tb * DM + j];
    __syncthreads();
    float uj = 0.f;
    for (int m = 0; m < DM; ++m) uj += fw2[m * DM + j] * cw[m];
    u[(size_t)tb * DM + j] = uj;
    float c = fb1[j];
    const float4* w1c = (const float4*)(fw1 + (size_t)j * (DINO + DM) + DINO);
    for (int d4 = 0; d4 < 64; ++d4) {
        float4 wv = w1c[d4];
        c += wv.x * cr[d4 * 4] + wv.y * cr[d4 * 4 + 1] +
             wv.z * cr[d4 * 4 + 2] + wv.w * cr[d4 * 4 + 3];
    }
    cpb[(size_t)tb * DM + j] = c;
    float s = fb2[j] * cw[j];
#pragma unroll
    for (int o = 32; o; o >>= 1) s += __shfl_xor(s, o);
    if ((j & 63) == 0) red[j >> 6] = s;
    __syncthreads();
    if (j == 0) sv[tb] = red[0] + red[1] + red[2] + red[3] + clsb[tok];
}

// ---------------------------------------------------------------------------
// out[b,p,t] = sigmoid( sum_k gelu(pp[b,p,k]+cpb[t,b,k]) * u[t,b,k] + s[t,b] )
// Block per (b,p); wave w handles t = w, w+4, ...
// ---------------------------------------------------------------------------
__global__ __launch_bounds__(256) void final_out(
    const float* __restrict__ pp, const float* __restrict__ cpb,
    const float* __restrict__ u, const float* __restrict__ sv,
    float* __restrict__ out)
{
    int bp = blockIdx.x;               // b*256+p
    int b = bp >> 8;
    int tid = threadIdx.x;
    int w = tid >> 6, l = tid & 63;
    const float* ppr = pp + (size_t)bp * DM;
    float p0 = ppr[l], p1 = ppr[64 + l], p2 = ppr[128 + l], p3 = ppr[192 + l];
    const float k2 = 0.70710678118654752440f;
    for (int t = w; t < TS; t += 4) {
        int tb = t * 32 + b;
        const float* cp = cpb + (size_t)tb * DM;
        const float* uu = u + (size_t)tb * DM;
        float x, v;
        x = p0 + cp[l];       v  = 0.5f * x * (1.f + erff(x * k2)) * uu[l];
        x = p1 + cp[64 + l];  v += 0.5f * x * (1.f + erff(x * k2)) * uu[64 + l];
        x = p2 + cp[128 + l]; v += 0.5f * x * (1.f + erff(x * k2)) * uu[128 + l];
        x = p3 + cp[192 + l]; v += 0.5f * x * (1.f + erff(x * k2)) * uu[192 + l];
#pragma unroll
        for (int off = 32; off; off >>= 1) v += __shfl_xor(v, off);
        if (l == 0) out[(size_t)bp * TS + t] = 1.f / (1.f + expf(-(v + sv[tb])));
    }
}

// ---------------------------------------------------------------------------
// Launcher
// ---------------------------------------------------------------------------
extern "C" void kernel_launch(void* const* d_in, const int* in_sizes, int n_in,
                              void* d_out, int out_size, void* d_ws, size_t ws_size,
                              hipStream_t stream)
{
    (void)in_sizes; (void)n_in; (void)out_size;
    const float* patches   = (const float*)d_in[0];
    const int*   tokens    = (const int*)  d_in[1];
    const float* embedding = (const float*)d_in[2];
    const float* pos_emb   = (const float*)d_in[3];
    const float* in_proj_w = (const float*)d_in[4];
    const float* in_proj_b = (const float*)d_in[5];
    const float* out_proj_w= (const float*)d_in[6];
    const float* out_proj_b= (const float*)d_in[7];
    const float* lin1_w    = (const float*)d_in[8];
    const float* lin1_b    = (const float*)d_in[9];
    const float* lin2_w    = (const float*)d_in[10];
    const float* lin2_b    = (const float*)d_in[11];
    const float* ln1_g     = (const float*)d_in[12];
    const float* ln1_b     = (const float*)d_in[13];
    const float* ln2_g     = (const float*)d_in[14];
    const float* ln2_b     = (const float*)d_in[15];
    const float* fus_w1    = (const float*)d_in[16];
    const float* fus_b1    = (const float*)d_in[17];
    const float* fus_w2    = (const float*)d_in[18];
    const float* fus_b2    = (const float*)d_in[19];
    const float* cls_w     = (const float*)d_in[20];
    const float* cls_b     = (const float*)d_in[21];

    if (ws_size < (size_t)WS_FLOATS * 4) return;

    float* ws   = (float*)d_ws;
    float* emb  = ws + OFF_EMB;
    float* qkv0 = ws + OFF_QKV0;
    float* x1   = ws + OFF_X1;
    float* h1   = ws + OFF_H1;
    float* big  = ws + OFF_BIG;       // ao0 / ff1-chunk / kv1 (sequential lifetimes)
    float* ao1  = ws + OFF_AO1;
    float* x2   = ws + OFF_X2;
    float* ff2  = ws + OFF_FF2;
    float* ctx  = ws + OFF_CTX;
    float* pp   = ws + OFF_PP;
    float* cpb  = ws + OFF_CPB;
    float* u    = ws + OFF_U;
    float* svec = ws + OFF_S;
    int*   map1 = (int*)(ws + OFF_MAP);
    int*   map2 = map1 + NTOK;

    // K0/K1: maps + embedding
    init_maps<<<98, 256, 0, stream>>>(map1, map2, ctx);
    embed_kernel<<<BB * TS, 256, 0, stream>>>(tokens, embedding, pos_emb, emb);

    // ---- Layer 0 ----
    // QKV (MFMA, fp32 interface): M=1280(10), N=768(6), K=256
    gemm_mf<false><<<dim3(6, 10), 256, 0, stream>>>(
        emb, DM, in_proj_w, DM, in_proj_b, qkv0, 768, DM);
    // attention -> packed fp32 ao0 (online-softmax prefix scan over t)
    attn0_kernel<<<NQ2, 256, 0, stream>>>(qkv0, big);
    // out-proj: x1 = ao0 @ Wout0^T + b : M=24960(195), N=256(2), K=256
    gemm_mf<false><<<dim3(2, 195), 256, 0, stream>>>(
        big, DM, out_proj_w, DM, out_proj_b, x1, DM, DM);
    ln_kernel<<<NTOK, 256, 0, stream>>>(x1, emb, map1, ln1_g, ln1_b);
    // FF in three 8320-row chunks (65*128; ff1-chunk fp32 aliases big)
    for (int c = 0; c < 3; ++c) {
        float* xa = x1 + (size_t)c * 8320 * DM;
        float* ha = h1 + (size_t)c * 8320 * DM;
        gemm_mf<true><<<dim3(8, 65), 256, 0, stream>>>(
            xa, DM, lin1_w, DM, lin1_b, big, DFF, DM);
        gemm_mf<false><<<dim3(2, 65), 256, 0, stream>>>(
            big, DFF, lin2_w, DFF, lin2_b, ha, DM, DFF);
    }
    ln_kernel<<<NTOK, 256, 0, stream>>>(h1, x1, nullptr, ln2_g, ln2_b);

    // ---- Layer 1 ----
    // K/V for all packed tokens: M=24960(195), N=512(4), K=256 (kv1 = big)
    gemm_mf<false><<<dim3(4, 195), 256, 0, stream>>>(
        h1, DM, in_proj_w + 768 * DM + 256 * DM, DM,
        in_proj_b + 768 + 256, big, 512, DM);
    attn1_kernel<<<NQ2, 256, 0, stream>>>(
        h1, big, in_proj_w + 768 * DM, in_proj_b + 768, ao1);
    gemm_nt<false><<<dim3(4, 20), 256, 0, stream>>>(
        ao1, DM, out_proj_w + DM * DM, DM, out_proj_b + DM, x2, DM, NQ2, DM, DM);
    ln_kernel<<<NQ2, 256, 0, stream>>>(x2, h1, map2, ln1_g + DM, ln1_b + DM);
    gemm_nt<true><<<dim3(16, 20), 256, 0, stream>>>(
        x2, DM, lin1_w + DFF * DM, DM, lin1_b + DFF, ff2, DFF, NQ2, DFF, DM);
    gemm_nt<false><<<dim3(4, 20), 256, 0, stream>>>(
        ff2, DFF, lin2_w + DM * DFF, DFF, lin2_b + DM, ctx + BB * DM, DM, NQ2, DM, DFF);
    ln_kernel<<<NQ2, 256, 0, stream>>>(ctx + BB * DM, x2, nullptr, ln2_g + DM, ln2_b + DM);

    // ---- Fusion head ----
    // pp = patches @ w1p^T : M=8192(64), N=256(2), K=384 (B = fus_w1, ldb=640)
    gemm_mf<false><<<dim3(2, 64), 256, 0, stream>>>(
        patches, DINO, fus_w1, DINO + DM, nullptr, pp, DM, DINO);
    fuse_prep<<<TS * BB, 256, 0, stream>>>(
        ctx, tokens, fus_w1, fus_b1, fus_w2, fus_b2, cls_w, cls_b, cpb, u, svec);
    final_out<<<BB * NPATCH, 256, 0, stream>>>(pp, cpb, u, svec, (float*)d_out);
}

// Round 6
// 581.946 us; speedup vs baseline: 2.3468x; 1.3696x over previous
//
#include <hip/hip_runtime.h>
#include <math.h>

// ---------------------------------------------------------------------------
// Problem constants
// ---------------------------------------------------------------------------
#define DM    256     // D_MODEL
#define NH    4
#define HD    64
#define TS    40
#define TM1   39
#define BB    32
#define DFF   1024
#define DINO  384
#define NPATCH 256
#define VOCAB 4096

#define NTOK  24960   // 780*32 packed (t, p<=t, b) tokens
#define NQ2   1248    // 39*32

typedef _Float16 f16;
typedef __attribute__((ext_vector_type(8))) _Float16 half8;  // MFMA A/B frag
typedef __attribute__((ext_vector_type(4))) float f32x4;

// ---------------------------------------------------------------------------
// Workspace layout (float offsets). Residual/LN-chain activations stay fp32
// (round-3 lesson). f16 only where the consumer re-rounds anyway (GEMM-A,
// attention KV, final gelu input pp). big aliases ao0h/ff1h/kv1h.
// ---------------------------------------------------------------------------
#define OFF_EMB    0u          /* f32 1280*256   327680 */
#define OFF_EMBH   327680u     /* f16 1280*256   163840 */
#define OFF_QKV0   491520u     /* f32 1280*768   983040 */
#define OFF_X1     1474560u    /* f32 24960*256  6389760 */
#define OFF_H1     7864320u    /* f32 24960*256  6389760 */
#define OFF_BIG    14254080u   /* 12779520 f: ao0h(12.8MB)/ff1h(51.1MB)/kv1h(25.6MB) */
#define OFF_AO1    27033600u   /* f32 1248*256   319488 */
#define OFF_X2     27353088u   /* f32 1248*256   319488 */
#define OFF_FF2    27672576u   /* f32 1248*1024  1277952 */
#define OFF_CTX    28950528u   /* f32 1280*256   327680 */
#define OFF_PPH    29278208u   /* f16 8192*256   1048576 */
#define OFF_CPB    30326784u   /* f32 1280*256   327680 */
#define OFF_U      30654464u   /* f32 1280*256   327680 */
#define OFF_S      30982144u   /* f32 1280(+pad) 2048 */
#define OFF_WQKVH  30984192u   /* f16 768*256    98304 */
#define OFF_WOH    31082496u   /* f16 256*256    32768 */
#define OFF_L1WH   31115264u   /* f16 1024*256   131072 */
#define OFF_L2WH   31246336u   /* f16 256*1024   131072 */
#define OFF_KVWH   31377408u   /* f16 512*256    65536 */
#define OFF_W1PH   31442944u   /* f16 256*384    49152 */
#define OFF_MAP    31492096u   /* int 24960+1248 26208 */
#define WS_FLOATS  (31492096u + 26208u)   /* 126.1 MB < 127.57 known-good */

// ---------------------------------------------------------------------------
// K0: init row maps + zero ctx[t=0]
// ---------------------------------------------------------------------------
__global__ void init_maps(int* __restrict__ map1, int* __restrict__ map2,
                          float* __restrict__ ctx)
{
    int idx = blockIdx.x * 256 + threadIdx.x;
    if (idx < BB * DM) ctx[idx] = 0.f;
    if (idx < NQ2) {
        int t = idx >> 5, b = idx & 31;
        map2[idx] = ((t * (t + 1)) / 2 + t) * 32 + b;      // packed row of (t,b,p=t)
    }
    if (idx < NTOK) {
        int q = idx >> 5, b = idx & 31;                    // q = tri(t)+p
        int t = 0;
        while (((t + 1) * (t + 2)) / 2 <= q) ++t;
        int p = q - (t * (t + 1)) / 2;
        map1[idx] = b * TS + p;                            // emb row of token
    }
}

// ---------------------------------------------------------------------------
// One-shot f32 -> f16 conversion of all GEMM weights (1015808 elements).
// ---------------------------------------------------------------------------
__global__ __launch_bounds__(256) void cvt_weights(
    const float* __restrict__ ipw, const float* __restrict__ opw,
    const float* __restrict__ l1w, const float* __restrict__ l2w,
    const float* __restrict__ fw1,
    f16* __restrict__ wqkvh, f16* __restrict__ woh, f16* __restrict__ l1wh,
    f16* __restrict__ l2wh, f16* __restrict__ kvwh, f16* __restrict__ w1ph)
{
    int i = blockIdx.x * 256 + threadIdx.x;
    if (i < 196608) { wqkvh[i] = (f16)ipw[i]; return; }
    i -= 196608;
    if (i < 65536) { woh[i] = (f16)opw[i]; return; }
    i -= 65536;
    if (i < 262144) { l1wh[i] = (f16)l1w[i]; return; }
    i -= 262144;
    if (i < 262144) { l2wh[i] = (f16)l2w[i]; return; }
    i -= 262144;
    if (i < 131072) { kvwh[i] = (f16)ipw[768 * 256 + 256 * 256 + i]; return; }
    i -= 131072;
    if (i < 98304) {
        int r = i / 384, c = i - r * 384;
        w1ph[i] = (f16)fw1[r * 640 + c];
    }
}

// ---------------------------------------------------------------------------
// K1: emb = embedding[tok] + pos (fp32 + f16 dual store)
// ---------------------------------------------------------------------------
__global__ __launch_bounds__(256) void embed_kernel(
    const int* __restrict__ tokens, const float* __restrict__ etab,
    const float* __restrict__ pos, float* __restrict__ emb,
    f16* __restrict__ embh)
{
    int r = blockIdx.x;            // b*40+p
    int p = r % TS;
    int j = threadIdx.x;
    int tok = tokens[r];
    float v = etab[(size_t)tok * DM + j] + pos[p * DM + j];
    emb[(size_t)r * DM + j] = v;
    embh[(size_t)r * DM + j] = (f16)v;
}

// ---------------------------------------------------------------------------
// fp32 GEMM (small M, M-tail OK) — layer-1 small GEMMs (M=1248).
// ---------------------------------------------------------------------------
template <bool RELU>
__global__ __launch_bounds__(256) void gemm_nt(
    const float* __restrict__ A, int lda,
    const float* __restrict__ B, int ldb,
    const float* __restrict__ bias,
    float* __restrict__ C, int ldc, int M, int N, int K)
{
    __shared__ __align__(16) float As[16][68];
    __shared__ __align__(16) float Bs[16][68];
    int m0 = blockIdx.y << 6, n0 = blockIdx.x << 6;
    int tid = threadIdx.x;
    int tx = tid & 15, ty = tid >> 4;
    int lm = tid >> 2, lk = (tid & 3) << 2;
    float acc[4][4] = {{0.f}};

    for (int k0 = 0; k0 < K; k0 += 16) {
        float4 av;
        int gm = m0 + lm;
        if (gm < M) av = *(const float4*)(A + (size_t)gm * lda + k0 + lk);
        else        av = make_float4(0.f, 0.f, 0.f, 0.f);
        float4 bv = *(const float4*)(B + (size_t)(n0 + lm) * ldb + k0 + lk);
        As[lk + 0][lm] = av.x; As[lk + 1][lm] = av.y;
        As[lk + 2][lm] = av.z; As[lk + 3][lm] = av.w;
        Bs[lk + 0][lm] = bv.x; Bs[lk + 1][lm] = bv.y;
        Bs[lk + 2][lm] = bv.z; Bs[lk + 3][lm] = bv.w;
        __syncthreads();
#pragma unroll
        for (int kk = 0; kk < 16; ++kk) {
            float4 a = *(const float4*)&As[kk][ty << 2];
            float4 b = *(const float4*)&Bs[kk][tx << 2];
            acc[0][0] += a.x * b.x; acc[0][1] += a.x * b.y; acc[0][2] += a.x * b.z; acc[0][3] += a.x * b.w;
            acc[1][0] += a.y * b.x; acc[1][1] += a.y * b.y; acc[1][2] += a.y * b.z; acc[1][3] += a.y * b.w;
            acc[2][0] += a.z * b.x; acc[2][1] += a.z * b.y; acc[2][2] += a.z * b.z; acc[2][3] += a.z * b.w;
            acc[3][0] += a.w * b.x; acc[3][1] += a.w * b.y; acc[3][2] += a.w * b.z; acc[3][3] += a.w * b.w;
        }
        __syncthreads();
    }
#pragma unroll
    for (int i = 0; i < 4; ++i) {
        int gm = m0 + (ty << 2) + i;
        if (gm >= M) continue;
#pragma unroll
        for (int jj = 0; jj < 4; ++jj) {
            int gn = n0 + (tx << 2) + jj;
            float v = acc[i][jj];
            if (bias) v += bias[gn];
            if (RELU) v = fmaxf(v, 0.f);
            C[(size_t)gm * ldc + gn] = v;
        }
    }
}

// ---------------------------------------------------------------------------
// MFMA GEMM, mixed input types. TA/TB = f16 (direct 16B stage) or float
// (convert to f16 in regs during staging — identical rounding to storing
// f16 upstream). fp32 accumulate. 128x128 tile, 4 waves, 4x4 MFMA 16x16x32.
// M%128==0, N%128==0, K%64==0.
// ---------------------------------------------------------------------------
__device__ __forceinline__ half8 load_frag8(const f16* p) { return *(const half8*)p; }
__device__ __forceinline__ half8 load_frag8(const float* p) {
    float4 a0 = *(const float4*)p;
    float4 a1 = *(const float4*)(p + 4);
    half8 h;
    h[0] = (f16)a0.x; h[1] = (f16)a0.y; h[2] = (f16)a0.z; h[3] = (f16)a0.w;
    h[4] = (f16)a1.x; h[5] = (f16)a1.y; h[6] = (f16)a1.z; h[7] = (f16)a1.w;
    return h;
}

template <typename TA, typename TB, bool RELU, bool OUTF16>
__global__ __launch_bounds__(256) void gemm_x(
    const TA* __restrict__ A, int lda,
    const TB* __restrict__ B, int ldb,
    const float* __restrict__ bias,
    void* __restrict__ Cv, int ldc, int K)
{
    __shared__ __align__(16) f16 lds[32 * 512];   // 32 frags x 512 halves
    int tid = threadIdx.x;
    int w = tid >> 6, l = tid & 63;
    int m0 = blockIdx.y << 7, n0 = blockIdx.x << 7;
    int lrow = l & 15;
    int lk8  = (l >> 4) << 3;
    int wm = w >> 1, wn = w & 1;

    f32x4 acc[4][4] = {};

    for (int k0 = 0; k0 < K; k0 += 64) {
#pragma unroll
        for (int j = 0; j < 4; ++j) {
            int f  = (w << 2) + j;         // 0..15
            int mi = f >> 1, kc = f & 1;
            const TA* ga = A + (size_t)(m0 + (mi << 4) + lrow) * lda + k0 + (kc << 5) + lk8;
            const TB* gb = B + (size_t)(n0 + (mi << 4) + lrow) * ldb + k0 + (kc << 5) + lk8;
            *(half8*)&lds[(f << 9) + (l << 3)]        = load_frag8(ga);
            *(half8*)&lds[((f + 16) << 9) + (l << 3)] = load_frag8(gb);
        }
        __syncthreads();
#pragma unroll
        for (int kc = 0; kc < 2; ++kc) {
            half8 af[4], bfr[4];
#pragma unroll
            for (int i = 0; i < 4; ++i) {
                int mi = (wm << 2) + i;
                int nj = (wn << 2) + i;
                af[i]  = *(half8*)&lds[(((mi << 1) | kc) << 9) + (l << 3)];
                bfr[i] = *(half8*)&lds[((16 + ((nj << 1) | kc)) << 9) + (l << 3)];
            }
#pragma unroll
            for (int i = 0; i < 4; ++i)
#pragma unroll
                for (int j2 = 0; j2 < 4; ++j2)
                    acc[i][j2] = __builtin_amdgcn_mfma_f32_16x16x32_f16(
                        af[i], bfr[j2], acc[i][j2], 0, 0, 0);
        }
        __syncthreads();
    }

    // epilogue: D col = lane&15, row = (lane>>4)*4 + reg   [m89/m91 verified]
    int colq = l & 15, rowq = (l >> 4) << 2;
#pragma unroll
    for (int i = 0; i < 4; ++i) {
        int gmb = m0 + (wm << 6) + (i << 4) + rowq;
#pragma unroll
        for (int j2 = 0; j2 < 4; ++j2) {
            int gn = n0 + (wn << 6) + (j2 << 4) + colq;
            float bv = bias ? bias[gn] : 0.f;
#pragma unroll
            for (int r = 0; r < 4; ++r) {
                float v = acc[i][j2][r] + bv;
                if (RELU) v = fmaxf(v, 0.f);
                if (OUTF16)
                    ((f16*)Cv)[(size_t)(gmb + r) * ldc + gn] = (f16)v;
                else
                    ((float*)Cv)[(size_t)(gmb + r) * ldc + gn] = v;
            }
        }
    }
}

// ---------------------------------------------------------------------------
// LayerNorm: one WAVE per row, float4 lanes, pure shuffle reductions.
// X fp32 in-place; optional fp32 residual via map.
// ---------------------------------------------------------------------------
__global__ __launch_bounds__(256) void ln_kernel(
    float* __restrict__ X, const float* __restrict__ res,
    const int* __restrict__ map, const float* __restrict__ g,
    const float* __restrict__ beta, int nrows)
{
    int r = blockIdx.x * 4 + (threadIdx.x >> 6);
    if (r >= nrows) return;
    int l = threadIdx.x & 63;
    float* xp = X + (size_t)r * DM + l * 4;
    float4 v = *(float4*)xp;
    if (res) {
        int rr = map ? map[r] : r;
        float4 rv = *(const float4*)(res + (size_t)rr * DM + l * 4);
        v.x += rv.x; v.y += rv.y; v.z += rv.z; v.w += rv.w;
    }
    float s = v.x + v.y + v.z + v.w;
#pragma unroll
    for (int o = 32; o; o >>= 1) s += __shfl_xor(s, o);
    float mean = s * (1.f / 256.f);
    float dx = v.x - mean, dy = v.y - mean, dz = v.z - mean, dw = v.w - mean;
    float s2 = dx * dx + dy * dy + dz * dz + dw * dw;
#pragma unroll
    for (int o = 32; o; o >>= 1) s2 += __shfl_xor(s2, o);
    float rstd = 1.f / sqrtf(s2 * (1.f / 256.f) + 1e-5f);
    float4 gv = *(const float4*)(g + l * 4);
    float4 bv = *(const float4*)(beta + l * 4);
    float4 ov;
    ov.x = dx * rstd * gv.x + bv.x;
    ov.y = dy * rstd * gv.y + bv.y;
    ov.z = dz * rstd * gv.z + bv.z;
    ov.w = dw * rstd * gv.w + bv.w;
    *(float4*)xp = ov;
}

// ---------------------------------------------------------------------------
// Layer-0 attention, online-softmax prefix scan (fp32 in, f16 packed out —
// ao0 is only consumed as GEMM-A, so f16 store = identical numerics).
// ---------------------------------------------------------------------------
__global__ __launch_bounds__(256) void attn0_kernel(
    const float* __restrict__ qkv, f16* __restrict__ ao)
{
    int bp = blockIdx.x;               // b*39 + p
    int b = bp / 39, p = bp % 39;
    int tid = threadIdx.x;
    int h = tid >> 6, l = tid & 63;

    float qv = qkv[(size_t)(b * TS + p) * 768 + h * 64 + l];

    int krow = (l < 39) ? l : 38;
    const float* Kr = qkv + (size_t)(b * TS + krow) * 768 + 256 + h * 64;
    float acc = 0.f;
#pragma unroll
    for (int d4 = 0; d4 < 16; ++d4) {
        float4 k4 = *(const float4*)(Kr + d4 * 4);
        acc += __shfl(qv, d4 * 4 + 0) * k4.x;
        acc += __shfl(qv, d4 * 4 + 1) * k4.y;
        acc += __shfl(qv, d4 * 4 + 2) * k4.z;
        acc += __shfl(qv, d4 * 4 + 3) * k4.w;
    }
    float s = acc * 0.125f;

    float m = -1e30f, lsum = 0.f, o = 0.f;
    for (int t = p; t < TM1; ++t) {
        float st = __shfl(s, t);
        float mnew = fmaxf(m, st);
        float c = __expf(m - mnew);
        float e = __expf(st - mnew);
        lsum = lsum * c + e;
        float vv = qkv[(size_t)(b * TS + t) * 768 + 512 + h * 64 + l];
        o = o * c + e * vv;
        m = mnew;
        int row = ((t * (t + 1)) >> 1) + p;
        ao[((size_t)row * 32 + b) * DM + h * 64 + l] = (f16)(o / lsum);
    }
}

// ---------------------------------------------------------------------------
// Layer-1 attention, LDS-staging-free. Block per (t,b): 4 waves = 4 heads.
// q = Wq @ h1[t,b,t] (fp32, h1 row in LDS); scores lane=key over f16 K;
// softmax wave-reduce; PV lane=dim over f16 V.
// ---------------------------------------------------------------------------
__global__ __launch_bounds__(256) void attn1_kernel(
    const float* __restrict__ h1, const f16* __restrict__ kv1,
    const float* __restrict__ Wq, const float* __restrict__ bq,
    float* __restrict__ ao1)
{
    int tb = blockIdx.x;
    int t = tb >> 5, b = tb & 31;
    int tid = threadIdx.x;
    int h = tid >> 6, l = tid & 63;
    int tri = (t * (t + 1)) >> 1;
    __shared__ float h1r[DM];
    h1r[tid] = h1[((size_t)(tri + t) * 32 + b) * DM + tid];
    __syncthreads();

    // q for dim l of head h
    float q = bq[h * 64 + l];
    const float4* w4 = (const float4*)(Wq + (size_t)(h * 64 + l) * DM);
    for (int k4 = 0; k4 < 64; ++k4) {
        float4 ww = w4[k4];
        q += ww.x * h1r[k4 * 4] + ww.y * h1r[k4 * 4 + 1] +
             ww.z * h1r[k4 * 4 + 2] + ww.w * h1r[k4 * 4 + 3];
    }

    // score: lane l = key row (clamped)
    int kr = (l <= t) ? l : t;
    const f16* Kp = kv1 + ((size_t)(tri + kr) * 32 + b) * 512 + h * 64;
    float sc = 0.f;
#pragma unroll
    for (int c = 0; c < 8; ++c) {
        half8 k8 = *(const half8*)(Kp + c * 8);
#pragma unroll
        for (int j = 0; j < 8; ++j)
            sc += __shfl(q, c * 8 + j) * (float)k8[j];
    }
    sc = (l <= t) ? sc * 0.125f : -1e30f;
    float m = sc;
#pragma unroll
    for (int o = 32; o; o >>= 1) m = fmaxf(m, __shfl_xor(m, o));
    float e = (l <= t) ? __expf(sc - m) : 0.f;
    float ss = e;
#pragma unroll
    for (int o = 32; o; o >>= 1) ss += __shfl_xor(ss, o);
    float a = e / ss;

    // PV: lane l = dim
    float o = 0.f;
    for (int k = 0; k <= t; ++k) {
        float ak = __shfl(a, k);
        o += ak * (float)kv1[((size_t)(tri + k) * 32 + b) * 512 + 256 + h * 64 + l];
    }
    ao1[(size_t)tb * DM + h * 64 + l] = o;
}

// ---------------------------------------------------------------------------
// per (t,b): u = fus_w2^T @ cls_w[tok]; cpb = ctx@w1c^T + fus_b1;
//            s = fus_b2 . cls_w[tok] + cls_b[tok]
// ---------------------------------------------------------------------------
__global__ __launch_bounds__(256) void fuse_prep(
    const float* __restrict__ ctx, const int* __restrict__ tokens,
    const float* __restrict__ fw1, const float* __restrict__ fb1,
    const float* __restrict__ fw2, const float* __restrict__ fb2,
    const float* __restrict__ clsw, const float* __restrict__ clsb,
    float* __restrict__ cpb, float* __restrict__ u, float* __restrict__ sv)
{
    int tb = blockIdx.x;               // t*32+b
    int t = tb >> 5, b = tb & 31;
    int j = threadIdx.x;
    __shared__ float cw[DM];
    __shared__ float cr[DM];
    __shared__ float red[4];
    int tok = tokens[b * TS + t];
    cw[j] = clsw[(size_t)tok * DM + j];
    cr[j] = ctx[(size_t)tb * DM + j];
    __syncthreads();
    float uj = 0.f;
    for (int m = 0; m < DM; ++m) uj += fw2[m * DM + j] * cw[m];
    u[(size_t)tb * DM + j] = uj;
    float c = fb1[j];
    const float4* w1c = (const float4*)(fw1 + (size_t)j * (DINO + DM) + DINO);
    for (int d4 = 0; d4 < 64; ++d4) {
        float4 wv = w1c[d4];
        c += wv.x * cr[d4 * 4] + wv.y * cr[d4 * 4 + 1] +
             wv.z * cr[d4 * 4 + 2] + wv.w * cr[d4 * 4 + 3];
    }
    cpb[(size_t)tb * DM + j] = c;
    float s = fb2[j] * cw[j];
#pragma unroll
    for (int o = 32; o; o >>= 1) s += __shfl_xor(s, o);
    if ((j & 63) == 0) red[j >> 6] = s;
    __syncthreads();
    if (j == 0) sv[tb] = red[0] + red[1] + red[2] + red[3] + clsb[tok];
}

// ---------------------------------------------------------------------------
// Fast gelu: AS 7.1.26 erf, |err| <= 1.5e-7 (logit impact < 1e-4).
// gelu(x) = 0.5x + 0.5|x|*erf(|x|/sqrt2)
// ---------------------------------------------------------------------------
__device__ __forceinline__ float gelu_f(float x)
{
    float ax = fabsf(x);
    float z  = ax * 0.70710678118654752440f;
    float tt = __builtin_amdgcn_rcpf(1.f + 0.3275911f * z);
    float pl = ((((1.061405429f * tt - 1.453152027f) * tt + 1.421413741f) * tt
                 - 0.284496736f) * tt + 0.254829592f) * tt;
    float E  = 1.f - pl * __expf(-z * z);
    return 0.5f * x + 0.5f * ax * E;
}

// ---------------------------------------------------------------------------
// out[b,p,t] = sigmoid( sum_k gelu(pp+cpb)*u + s ). Block per (b,p);
// wave w: t = w, w+4, ...; lane l covers k = 4l..4l+3 (float4).
// ---------------------------------------------------------------------------
__global__ __launch_bounds__(256) void final_out(
    const f16* __restrict__ pp, const float* __restrict__ cpb,
    const float* __restrict__ u, const float* __restrict__ sv,
    float* __restrict__ out)
{
    int bp = blockIdx.x;               // b*256+p
    int b = bp >> 8;
    int tid = threadIdx.x;
    int w = tid >> 6, l = tid & 63;
    const f16* ppr = pp + (size_t)bp * DM + l * 4;
    float p0 = (float)ppr[0], p1 = (float)ppr[1];
    float p2 = (float)ppr[2], p3 = (float)ppr[3];
    for (int t = w; t < TS; t += 4) {
        int tb = t * 32 + b;
        float4 cp = *(const float4*)(cpb + (size_t)tb * DM + l * 4);
        float4 uu = *(const float4*)(u + (size_t)tb * DM + l * 4);
        float v = gelu_f(p0 + cp.x) * uu.x + gelu_f(p1 + cp.y) * uu.y +
                  gelu_f(p2 + cp.z) * uu.z + gelu_f(p3 + cp.w) * uu.w;
#pragma unroll
        for (int off = 32; off; off >>= 1) v += __shfl_xor(v, off);
        if (l == 0) out[(size_t)bp * TS + t] = 1.f / (1.f + __expf(-(v + sv[tb])));
    }
}

// ---------------------------------------------------------------------------
// Launcher
// ---------------------------------------------------------------------------
extern "C" void kernel_launch(void* const* d_in, const int* in_sizes, int n_in,
                              void* d_out, int out_size, void* d_ws, size_t ws_size,
                              hipStream_t stream)
{
    (void)in_sizes; (void)n_in; (void)out_size;
    const float* patches   = (const float*)d_in[0];
    const int*   tokens    = (const int*)  d_in[1];
    const float* embedding = (const float*)d_in[2];
    const float* pos_emb   = (const float*)d_in[3];
    const float* in_proj_w = (const float*)d_in[4];
    const float* in_proj_b = (const float*)d_in[5];
    const float* out_proj_w= (const float*)d_in[6];
    const float* out_proj_b= (const float*)d_in[7];
    const float* lin1_w    = (const float*)d_in[8];
    const float* lin1_b    = (const float*)d_in[9];
    const float* lin2_w    = (const float*)d_in[10];
    const float* lin2_b    = (const float*)d_in[11];
    const float* ln1_g     = (const float*)d_in[12];
    const float* ln1_b     = (const float*)d_in[13];
    const float* ln2_g     = (const float*)d_in[14];
    const float* ln2_b     = (const float*)d_in[15];
    const float* fus_w1    = (const float*)d_in[16];
    const float* fus_b1    = (const float*)d_in[17];
    const float* fus_w2    = (const float*)d_in[18];
    const float* fus_b2    = (const float*)d_in[19];
    const float* cls_w     = (const float*)d_in[20];
    const float* cls_b     = (const float*)d_in[21];

    if (ws_size < (size_t)WS_FLOATS * 4) return;

    float* ws   = (float*)d_ws;
    float* emb  = ws + OFF_EMB;
    f16*   embh = (f16*)(ws + OFF_EMBH);
    float* qkv0 = ws + OFF_QKV0;
    float* x1   = ws + OFF_X1;
    float* h1   = ws + OFF_H1;
    float* big  = ws + OFF_BIG;
    f16*   ao0h = (f16*)big;          // 24960*256 f16
    f16*   ff1h = (f16*)big;          // 24960*1024 f16 (51.1 MB, exact)
    f16*   kv1h = (f16*)big;          // 24960*512 f16
    float* ao1  = ws + OFF_AO1;
    float* x2   = ws + OFF_X2;
    float* ff2  = ws + OFF_FF2;
    float* ctx  = ws + OFF_CTX;
    f16*   pph  = (f16*)(ws + OFF_PPH);
    float* cpb  = ws + OFF_CPB;
    float* u    = ws + OFF_U;
    float* svec = ws + OFF_S;
    f16*   wqkvh= (f16*)(ws + OFF_WQKVH);
    f16*   woh  = (f16*)(ws + OFF_WOH);
    f16*   l1wh = (f16*)(ws + OFF_L1WH);
    f16*   l2wh = (f16*)(ws + OFF_L2WH);
    f16*   kvwh = (f16*)(ws + OFF_KVWH);
    f16*   w1ph = (f16*)(ws + OFF_W1PH);
    int*   map1 = (int*)(ws + OFF_MAP);
    int*   map2 = map1 + NTOK;

    init_maps<<<98, 256, 0, stream>>>(map1, map2, ctx);
    embed_kernel<<<BB * TS, 256, 0, stream>>>(tokens, embedding, pos_emb, emb, embh);
    cvt_weights<<<3968, 256, 0, stream>>>(in_proj_w, out_proj_w, lin1_w, lin2_w,
                                          fus_w1, wqkvh, woh, l1wh, l2wh, kvwh, w1ph);

    // ---- Layer 0 ----
    // QKV: M=1280(10), N=768(6), K=256
    gemm_x<f16, f16, false, false><<<dim3(6, 10), 256, 0, stream>>>(
        embh, DM, wqkvh, DM, in_proj_b, qkv0, 768, DM);
    attn0_kernel<<<NQ2, 256, 0, stream>>>(qkv0, ao0h);
    // out-proj: M=24960(195), N=256(2), K=256
    gemm_x<f16, f16, false, false><<<dim3(2, 195), 256, 0, stream>>>(
        ao0h, DM, woh, DM, out_proj_b, x1, DM, DM);
    ln_kernel<<<6240, 256, 0, stream>>>(x1, emb, map1, ln1_g, ln1_b, NTOK);
    // FF full-M: lin1 M=24960, N=1024(8); lin2 N=256(2), K=1024
    gemm_x<float, f16, true, true><<<dim3(8, 195), 256, 0, stream>>>(
        x1, DM, l1wh, DM, lin1_b, ff1h, DFF, DM);
    gemm_x<f16, f16, false, false><<<dim3(2, 195), 256, 0, stream>>>(
        ff1h, DFF, l2wh, DFF, lin2_b, h1, DM, DFF);
    ln_kernel<<<6240, 256, 0, stream>>>(h1, x1, nullptr, ln2_g, ln2_b, NTOK);

    // ---- Layer 1 ----
    // K/V: M=24960(195), N=512(4), K=256 -> f16 packed (kv1h aliases big)
    gemm_x<float, f16, false, true><<<dim3(4, 195), 256, 0, stream>>>(
        h1, DM, kvwh, DM, in_proj_b + 768 + 256, kv1h, 512, DM);
    attn1_kernel<<<NQ2, 256, 0, stream>>>(
        h1, kv1h, in_proj_w + 768 * DM, in_proj_b + 768, ao1);
    gemm_nt<false><<<dim3(4, 20), 256, 0, stream>>>(
        ao1, DM, out_proj_w + DM * DM, DM, out_proj_b + DM, x2, DM, NQ2, DM, DM);
    ln_kernel<<<312, 256, 0, stream>>>(x2, h1, map2, ln1_g + DM, ln1_b + DM, NQ2);
    gemm_nt<true><<<dim3(16, 20), 256, 0, stream>>>(
        x2, DM, lin1_w + DFF * DM, DM, lin1_b + DFF, ff2, DFF, NQ2, DFF, DM);
    gemm_nt<false><<<dim3(4, 20), 256, 0, stream>>>(
        ff2, DFF, lin2_w + DM * DFF, DFF, lin2_b + DM, ctx + BB * DM, DM, NQ2, DM, DFF);
    ln_kernel<<<312, 256, 0, stream>>>(ctx + BB * DM, x2, nullptr, ln2_g + DM, ln2_b + DM, NQ2);

    // ---- Fusion head ----
    // pp = patches @ w1p^T: M=8192(64), N=256(2), K=384 -> f16
    gemm_x<float, f16, false, true><<<dim3(2, 64), 256, 0, stream>>>(
        patches, DINO, w1ph, DINO, nullptr, pph, DM, DINO);
    fuse_prep<<<TS * BB, 256, 0, stream>>>(
        ctx, tokens, fus_w1, fus_b1, fus_w2, fus_b2, cls_w, cls_b, cpb, u, svec);
    final_out<<<BB * NPATCH, 256, 0, stream>>>(pph, cpb, u, svec, (float*)d_out);
}